// Round 6
// baseline (140.752 us; speedup 1.0000x reference)
//
#include <hip/hip_runtime.h>

#define B_  8
#define TQ  256
#define TV  512
#define DD  256
#define ALGS 520  // alg row stride (score_part): quad-write banks -> <=2-way = free

__device__ __forceinline__ float fast_exp2(float x) {
#if __has_builtin(__builtin_amdgcn_exp2f)
  return __builtin_amdgcn_exp2f(x);
#else
  return __exp2f(x);
#endif
}
__device__ __forceinline__ float fast_rcp(float x) {
#if __has_builtin(__builtin_amdgcn_rcpf)
  return __builtin_amdgcn_rcpf(x);
#else
  return 1.0f / x;
#endif
}

// ---------------------------------------------------------------------------
// Fused projections with EXP epilogue (identical to prior rounds — validated):
//   Eq = exp2(SC*(query@W1 + b1)),  Ev = exp2(SC*(value@W2 + b2))
// ---------------------------------------------------------------------------
__global__ __launch_bounds__(256) void proj_fused(
    const float* __restrict__ query, const float* __restrict__ value,
    const float* __restrict__ W1, const float* __restrict__ b1,
    const float* __restrict__ W2, const float* __restrict__ b2,
    float* __restrict__ qp, float* __restrict__ vp, float scale) {
  __shared__ float As[2][32][64];  // [p][k][m ^ sw(k)]
  __shared__ float Bs[2][32][64];  // [p][k][n]
  const int t  = threadIdx.x;
  const int rt = blockIdx.x;
  const int bn = blockIdx.y << 6;

  const float* A; const float* W; const float* bias; float* out; int row0;
  if (rt < 32) { row0 = rt << 6;        A = query; W = W1; bias = b1; out = qp; }
  else         { row0 = (rt - 32) << 6; A = value; W = W2; bias = b2; out = vp; }

  const int tx = t & 15, ty = t >> 4;
  const int aar = t >> 3, aac = (t & 7) << 2;
  const int bbr = t >> 4, bbc = (t & 15) << 2;

  float4 ra[2], rb[2];
#pragma unroll
  for (int it = 0; it < 2; ++it) {
    ra[it] = *(const float4*)(A + (size_t)(row0 + (it << 5) + aar) * DD + aac);
    rb[it] = *(const float4*)(W + (size_t)((it << 4) + bbr) * DD + bn + bbc);
  }
#pragma unroll
  for (int it = 0; it < 2; ++it) {
    const int m = (it << 5) + aar;
#pragma unroll
    for (int c = 0; c < 4; ++c) {
      const int k = aac + c;
      As[0][k][m ^ (((k >> 2) & 7) << 2)] = (&ra[it].x)[c];
    }
    *(float4*)&Bs[0][(it << 4) + bbr][bbc] = rb[it];
  }
  __syncthreads();

  float acc[4][4] = {{0.f,0.f,0.f,0.f},{0.f,0.f,0.f,0.f},
                     {0.f,0.f,0.f,0.f},{0.f,0.f,0.f,0.f}};
  int p = 0;

  for (int k0 = 0; k0 < 256; k0 += 32) {
    const bool more = (k0 + 32) < 256;
    if (more) {
#pragma unroll
      for (int it = 0; it < 2; ++it) {
        ra[it] = *(const float4*)(A + (size_t)(row0 + (it << 5) + aar) * DD + k0 + 32 + aac);
        rb[it] = *(const float4*)(W + (size_t)(k0 + 32 + (it << 4) + bbr) * DD + bn + bbc);
      }
    }
#pragma unroll
    for (int k = 0; k < 32; ++k) {
      float4 aq = *(const float4*)&As[p][k][(ty << 2) ^ (((k >> 2) & 7) << 2)];
      float4 bq = *(const float4*)&Bs[p][k][tx << 2];
      acc[0][0] = fmaf(aq.x, bq.x, acc[0][0]); acc[0][1] = fmaf(aq.x, bq.y, acc[0][1]);
      acc[0][2] = fmaf(aq.x, bq.z, acc[0][2]); acc[0][3] = fmaf(aq.x, bq.w, acc[0][3]);
      acc[1][0] = fmaf(aq.y, bq.x, acc[1][0]); acc[1][1] = fmaf(aq.y, bq.y, acc[1][1]);
      acc[1][2] = fmaf(aq.y, bq.z, acc[1][2]); acc[1][3] = fmaf(aq.y, bq.w, acc[1][3]);
      acc[2][0] = fmaf(aq.z, bq.x, acc[2][0]); acc[2][1] = fmaf(aq.z, bq.y, acc[2][1]);
      acc[2][2] = fmaf(aq.z, bq.z, acc[2][2]); acc[2][3] = fmaf(aq.z, bq.w, acc[2][3]);
      acc[3][0] = fmaf(aq.w, bq.x, acc[3][0]); acc[3][1] = fmaf(aq.w, bq.y, acc[3][1]);
      acc[3][2] = fmaf(aq.w, bq.z, acc[3][2]); acc[3][3] = fmaf(aq.w, bq.w, acc[3][3]);
    }
    if (more) {
      const int q = p ^ 1;
#pragma unroll
      for (int it = 0; it < 2; ++it) {
        const int m = (it << 5) + aar;
#pragma unroll
        for (int c = 0; c < 4; ++c) {
          const int k = aac + c;
          As[q][k][m ^ (((k >> 2) & 7) << 2)] = (&ra[it].x)[c];
        }
        *(float4*)&Bs[q][(it << 4) + bbr][bbc] = rb[it];
      }
      __syncthreads();
      p = q;
    }
  }

  float4 bvv = *(const float4*)&bias[bn + (tx << 2)];
#pragma unroll
  for (int r = 0; r < 4; ++r) {
    float4 o;
    o.x = fast_exp2(scale * (acc[r][0] + bvv.x));
    o.y = fast_exp2(scale * (acc[r][1] + bvv.y));
    o.z = fast_exp2(scale * (acc[r][2] + bvv.z));
    o.w = fast_exp2(scale * (acc[r][3] + bvv.w));
    *(float4*)(out + (size_t)(row0 + (ty << 2) + r) * DD + bn + (tx << 2)) = o;
  }
}

// ---------------------------------------------------------------------------
// STAGE A: partial score over a 128-wide d-slice (R5 verbatim — validated).
// 1024 blocks x 512 threads, 4 blocks/CU (100% occupancy cap) at CONSTANT
// total Ev traffic.
// ---------------------------------------------------------------------------
__global__ __launch_bounds__(512, 8) void score_part(
    const float* __restrict__ qp, const float* __restrict__ vp,
    float* __restrict__ Sp) {
  __shared__ float qs[4 * 128];    // Eq half-rows, 2 KB
  __shared__ float alg[4 * ALGS];  // raw S partials, 8.3 KB

  const int t    = threadIdx.x;
  const int lane = t & 63;
  const int wv   = t >> 6;        // 0..7
  const int jj   = lane >> 2;     // 0..15
  const int dq   = lane & 3;      // d-quarter phase
  const int bx   = blockIdx.x;
  const int bb   = bx & 7;        // batch -> XCD locality
  const int rest = bx >> 3;       // 0..127
  const int iblk = rest & 63;     // q-row group
  const int i0   = iblk << 2;
  const int dh   = rest >> 6;     // d-half 0/1
  const int d0   = dh << 7;

  const float* vpb = vp + (size_t)bb * TV * DD;
  const float* qb  = qp + (size_t)(bb * TQ + i0) * DD + d0;

  // stage 4 Eq half-rows (128 floats each), 1 float per thread
  qs[t] = qb[(size_t)(t >> 7) * DD + (t & 127)];
  __syncthreads();

  // per-lane Ev row bases: j(jg) = jg*128 + wv*16 + jj
  const int jb = (wv << 4) + jj;
  const float* vr0 = vpb + (size_t)jb * DD + d0 + (dq << 2);
  const float* vr1 = vr0 + 128 * DD;
  const float* vr2 = vr0 + 256 * DD;
  const float* vr3 = vr0 + 384 * DD;
  const float* qlane = qs + (dq << 2);

  float acc[4][4] = {{0.f,0.f,0.f,0.f},{0.f,0.f,0.f,0.f},
                     {0.f,0.f,0.f,0.f},{0.f,0.f,0.f,0.f}};

#pragma unroll 4
  for (int k = 0; k < 8; ++k) {
    const int doff = k << 4;  // 16 floats per k-step
    float4 q0 = *(const float4*)(qlane + 0 * 128 + doff);
    float4 q1 = *(const float4*)(qlane + 1 * 128 + doff);
    float4 q2 = *(const float4*)(qlane + 2 * 128 + doff);
    float4 q3 = *(const float4*)(qlane + 3 * 128 + doff);
#pragma unroll
    for (int jg = 0; jg < 4; ++jg) {
      const float* vrp = (jg == 0) ? vr0 : (jg == 1) ? vr1 : (jg == 2) ? vr2 : vr3;
      float4 v4 = *(const float4*)(vrp + doff);
#pragma unroll
      for (int i = 0; i < 4; ++i) {
        const float4 q4 = (i == 0) ? q0 : (i == 1) ? q1 : (i == 2) ? q2 : q3;
        float a = q4.x * v4.x, b = q4.y * v4.y;
        float c = q4.z * v4.z, d = q4.w * v4.w;
        float sab = a + b,  scd = c + d;
        float Q1 = fmaf(a, b, sab + 1.f);   // (1+a)(1+b)
        float Q2 = fmaf(c, d, scd + 1.f);   // (1+c)(1+d)
        float N  = fmaf(scd + 2.f, Q1, (sab + 2.f) * Q2);
        acc[i][jg] = fmaf(N, fast_rcp(Q1 * Q2), acc[i][jg]);
      }
    }
  }

  // quad butterfly: combine the 4 d-quarter partials within each jj
#pragma unroll
  for (int i = 0; i < 4; ++i)
#pragma unroll
    for (int jg = 0; jg < 4; ++jg) {
      acc[i][jg] += __shfl_xor(acc[i][jg], 1, 64);
      acc[i][jg] += __shfl_xor(acc[i][jg], 2, 64);
    }
  // lane writes the i = dq slice (banks <=2-way with ALGS=520)
#pragma unroll
  for (int jg = 0; jg < 4; ++jg) {
    float x = (dq == 0) ? acc[0][jg] : (dq == 1) ? acc[1][jg]
            : (dq == 2) ? acc[2][jg] : acc[3][jg];
    alg[dq * ALGS + (jg << 7) + jb] = x;
  }
  __syncthreads();

  // dump partial S[4][512] -> ws (coalesced float4 per thread)
  float* sb = Sp + ((size_t)(dh * 8 + bb) * 64 + iblk) * (4 * 512);
  const int r = t >> 7, c = (t & 127) << 2;
  *(float4*)(sb + r * 512 + c) = *(const float4*)&alg[r * ALGS + c];
}

// ---------------------------------------------------------------------------
// STAGE B: combine S halves + softmax + context + concat + alignment_t,
// SPLIT BY FEATURE-HALF fh: 1024 blocks x 512 threads -> 4 blocks/CU
// (Stage B was the round-5 laggard at 2 blocks/CU). Per-block value traffic
// halves as block count doubles -> total traffic constant. Softmax is
// recomputed in both halves (16 float4 reads + ~40 VALU — cheap).
// LDS = 8 KB alg (unpadded [4][512]: softmax writes 2-way-free, context
// reads wave-broadcast) + 32 KB ctxp = 40.0 KB -> exactly 4 blocks/CU.
// Context: 16 j-strips x 32 j; thread (s = t>>5, f4 = (t&31)<<2 + fh*128).
// Value loads: 32 lanes x 16B = 512B contiguous per row. alg reads: 2
// distinct addrs/wave (s = 2w, 2w+1) -> 2-way broadcast, free.
// ---------------------------------------------------------------------------
__global__ __launch_bounds__(512, 8) void ctx_part(
    const float* __restrict__ Sp, const float* __restrict__ value,
    const float* __restrict__ query, float* __restrict__ out1,
    float* __restrict__ out2) {
  __shared__ float alg[4 * 512];       // alignment, 8 KB (no pad needed)
  __shared__ float ctxp[16][4][128];   // context strip partials, 32 KB

  const int t    = threadIdx.x;
  const int lane = t & 63;
  const int wv   = t >> 6;        // 0..7
  const int bx   = blockIdx.x;
  const int bb   = bx & 7;        // batch -> XCD locality
  const int rest = bx >> 3;       // 0..127
  const int iblk = rest & 63;     // q-row group
  const int i0   = iblk << 2;
  const int fh   = rest >> 6;     // feature-half 0/1

  const float* slo = Sp + ((size_t)(0 * 8 + bb) * 64 + iblk) * (4 * 512);
  const float* shi = Sp + ((size_t)(1 * 8 + bb) * 64 + iblk) * (4 * 512);

  // ---- context addressing + first-chunk prefetch (hides under softmax) ----
  const int s  = t >> 5;                       // j-strip 0..15: [s*32, s*32+32)
  const int f4 = ((t & 31) << 2) + (fh << 7);  // feature base in this half
  const float* vb  = value + (size_t)bb * TV * DD;
  const float* vsp = vb + (size_t)(s << 5) * DD + f4;

  float4 pv0 = *(const float4*)(vsp + 0 * DD);
  float4 pv1 = *(const float4*)(vsp + 1 * DD);
  float4 pv2 = *(const float4*)(vsp + 2 * DD);
  float4 pv3 = *(const float4*)(vsp + 3 * DD);

  // ---- softmax over j: wave wv (<4) owns row wv ----
  // score = 256 - 2*S -> max(score) <-> min(S); w = exp2(CC*(Smin - S))
  if (wv < 4) {
    float sv[8];
#pragma unroll
    for (int c = 0; c < 8; ++c)
      sv[c] = slo[wv * 512 + (c << 6) + lane] + shi[wv * 512 + (c << 6) + lane];
    float mn = sv[0];
#pragma unroll
    for (int c = 1; c < 8; ++c) mn = fminf(mn, sv[c]);
#pragma unroll
    for (int m = 1; m < 64; m <<= 1) mn = fminf(mn, __shfl_xor(mn, m, 64));

    const float CC = 2.8853900817779268f;  // 2*log2(e)
    float p[8];
    float sum = 0.f;
#pragma unroll
    for (int c = 0; c < 8; ++c) { p[c] = fast_exp2(CC * (mn - sv[c])); sum += p[c]; }
#pragma unroll
    for (int m = 1; m < 64; m <<= 1) sum += __shfl_xor(sum, m, 64);
    const float inv = fast_rcp(sum);
#pragma unroll
    for (int c = 0; c < 8; ++c) alg[wv * 512 + (c << 6) + lane] = p[c] * inv;
  }
  __syncthreads();

  // ---- alignment_t write (fh==0 blocks only): out2[b][j][i0..i0+3] ----
  if (fh == 0) {
    const int j = t;  // 0..511
    float4 av = make_float4(alg[j], alg[512 + j], alg[1024 + j], alg[1536 + j]);
    *(float4*)(out2 + (size_t)(bb * TV + j) * TQ + i0) = av;
  }

  // ---- context: thread (s, f4) does 4 rows x 4 features over 32 j ----
  float c4[4][4] = {{0.f,0.f,0.f,0.f},{0.f,0.f,0.f,0.f},
                    {0.f,0.f,0.f,0.f},{0.f,0.f,0.f,0.f}};
  const int jbase = s << 5;
  {
    // u = 0 chunk from prefetched registers
#pragma unroll
    for (int i = 0; i < 4; ++i) {
      float4 ai = *(const float4*)&alg[i * 512 + jbase];
      c4[i][0] = fmaf(ai.x, pv0.x, c4[i][0]); c4[i][1] = fmaf(ai.x, pv0.y, c4[i][1]);
      c4[i][2] = fmaf(ai.x, pv0.z, c4[i][2]); c4[i][3] = fmaf(ai.x, pv0.w, c4[i][3]);
      c4[i][0] = fmaf(ai.y, pv1.x, c4[i][0]); c4[i][1] = fmaf(ai.y, pv1.y, c4[i][1]);
      c4[i][2] = fmaf(ai.y, pv1.z, c4[i][2]); c4[i][3] = fmaf(ai.y, pv1.w, c4[i][3]);
      c4[i][0] = fmaf(ai.z, pv2.x, c4[i][0]); c4[i][1] = fmaf(ai.z, pv2.y, c4[i][1]);
      c4[i][2] = fmaf(ai.z, pv2.z, c4[i][2]); c4[i][3] = fmaf(ai.z, pv2.w, c4[i][3]);
      c4[i][0] = fmaf(ai.w, pv3.x, c4[i][0]); c4[i][1] = fmaf(ai.w, pv3.y, c4[i][1]);
      c4[i][2] = fmaf(ai.w, pv3.z, c4[i][2]); c4[i][3] = fmaf(ai.w, pv3.w, c4[i][3]);
    }
  }
#pragma unroll
  for (int u = 4; u < 32; u += 4) {
    float4 v0 = *(const float4*)(vsp + (size_t)(u + 0) * DD);
    float4 v1 = *(const float4*)(vsp + (size_t)(u + 1) * DD);
    float4 v2 = *(const float4*)(vsp + (size_t)(u + 2) * DD);
    float4 v3 = *(const float4*)(vsp + (size_t)(u + 3) * DD);
#pragma unroll
    for (int i = 0; i < 4; ++i) {
      float4 ai = *(const float4*)&alg[i * 512 + jbase + u];
      c4[i][0] = fmaf(ai.x, v0.x, c4[i][0]); c4[i][1] = fmaf(ai.x, v0.y, c4[i][1]);
      c4[i][2] = fmaf(ai.x, v0.z, c4[i][2]); c4[i][3] = fmaf(ai.x, v0.w, c4[i][3]);
      c4[i][0] = fmaf(ai.y, v1.x, c4[i][0]); c4[i][1] = fmaf(ai.y, v1.y, c4[i][1]);
      c4[i][2] = fmaf(ai.y, v1.z, c4[i][2]); c4[i][3] = fmaf(ai.y, v1.w, c4[i][3]);
      c4[i][0] = fmaf(ai.z, v2.x, c4[i][0]); c4[i][1] = fmaf(ai.z, v2.y, c4[i][1]);
      c4[i][2] = fmaf(ai.z, v2.z, c4[i][2]); c4[i][3] = fmaf(ai.z, v2.w, c4[i][3]);
      c4[i][0] = fmaf(ai.w, v3.x, c4[i][0]); c4[i][1] = fmaf(ai.w, v3.y, c4[i][1]);
      c4[i][2] = fmaf(ai.w, v3.z, c4[i][2]); c4[i][3] = fmaf(ai.w, v3.w, c4[i][3]);
    }
  }
  // stash strip partials: [s][i][fi4..fi4+3]
  const int fi4 = (t & 31) << 2;
#pragma unroll
  for (int i = 0; i < 4; ++i)
    *(float4*)&ctxp[s][i][fi4] = make_float4(c4[i][0], c4[i][1], c4[i][2], c4[i][3]);
  __syncthreads();

  // ---- strip reduction + concat output (this block's feature-half) ----
  // 512 ctx outputs (4 rows x 128 f) + 512 query copies; 1 each per thread.
  const int ri = t >> 7;        // row 0..3
  const int ff = t & 127;       // feature within half
  float sum = 0.f;
#pragma unroll
  for (int ss = 0; ss < 16; ++ss) sum += ctxp[ss][ri][ff];
  const float* qg = query + (size_t)(bb * TQ + i0) * DD;
  float* o = out1 + (size_t)(bb * TQ + i0) * (2 * DD);
  o[ri * 512 + (fh << 7) + ff] = sum;
  o[ri * 512 + 256 + (fh << 7) + ff] = qg[ri * DD + (fh << 7) + ff];
}

// ---------------------------------------------------------------------------
// FALLBACK (ws too small for Sp): R2 monolithic attn, verbatim (46.6 us).
// ---------------------------------------------------------------------------
__global__ __launch_bounds__(512, 4) void attn_mono(
    const float* __restrict__ qp, const float* __restrict__ vp,
    const float* __restrict__ value, const float* __restrict__ query,
    float* __restrict__ out1, float* __restrict__ out2) {
  __shared__ float qs[4 * 256];
  __shared__ float alg[4 * ALGS];
  __shared__ float ctxp[8][4][256];

  const int t    = threadIdx.x;
  const int lane = t & 63;
  const int wv   = t >> 6;
  const int jj   = lane >> 2;
  const int dq   = lane & 3;
  const int bb   = blockIdx.x & 7;
  const int i0   = (blockIdx.x >> 3) << 2;

  const float* vpb = vp + (size_t)bb * TV * DD;
  const float* qb  = qp + (size_t)(bb * TQ + i0) * DD;

  if (t < 256) {
    const int qi = t >> 6, qc = (t & 63) << 2;
    *(float4*)&qs[qi * 256 + qc] = *(const float4*)(qb + (size_t)qi * DD + qc);
  }
  __syncthreads();

  const int jb = (wv << 4) + jj;
  const float* vr0 = vpb + (size_t)jb * DD + (dq << 2);
  const float* vr1 = vr0 + 128 * DD;
  const float* vr2 = vr0 + 256 * DD;
  const float* vr3 = vr0 + 384 * DD;
  const float* qlane = qs + (dq << 2);

  float acc[4][4] = {{0.f,0.f,0.f,0.f},{0.f,0.f,0.f,0.f},
                     {0.f,0.f,0.f,0.f},{0.f,0.f,0.f,0.f}};

#pragma unroll 4
  for (int k = 0; k < 16; ++k) {
    const int doff = k << 4;
    float4 q0 = *(const float4*)(qlane + 0 * 256 + doff);
    float4 q1 = *(const float4*)(qlane + 1 * 256 + doff);
    float4 q2 = *(const float4*)(qlane + 2 * 256 + doff);
    float4 q3 = *(const float4*)(qlane + 3 * 256 + doff);
#pragma unroll
    for (int jg = 0; jg < 4; ++jg) {
      const float* vrp = (jg == 0) ? vr0 : (jg == 1) ? vr1 : (jg == 2) ? vr2 : vr3;
      float4 v4 = *(const float4*)(vrp + doff);
#pragma unroll
      for (int i = 0; i < 4; ++i) {
        const float4 q4 = (i == 0) ? q0 : (i == 1) ? q1 : (i == 2) ? q2 : q3;
        float a = q4.x * v4.x, b = q4.y * v4.y;
        float c = q4.z * v4.z, d = q4.w * v4.w;
        float sab = a + b,  scd = c + d;
        float Q1 = fmaf(a, b, sab + 1.f);
        float Q2 = fmaf(c, d, scd + 1.f);
        float N  = fmaf(scd + 2.f, Q1, (sab + 2.f) * Q2);
        acc[i][jg] = fmaf(N, fast_rcp(Q1 * Q2), acc[i][jg]);
      }
    }
  }

#pragma unroll
  for (int i = 0; i < 4; ++i)
#pragma unroll
    for (int jg = 0; jg < 4; ++jg) {
      acc[i][jg] += __shfl_xor(acc[i][jg], 1, 64);
      acc[i][jg] += __shfl_xor(acc[i][jg], 2, 64);
    }
#pragma unroll
  for (int jg = 0; jg < 4; ++jg) {
    float x = (dq == 0) ? acc[0][jg] : (dq == 1) ? acc[1][jg]
            : (dq == 2) ? acc[2][jg] : acc[3][jg];
    alg[dq * ALGS + (jg << 7) + jb] = x;
  }

  const int f4 = (t & 63) << 2;
  const int s  = t >> 6;
  const float* vb  = value + (size_t)bb * TV * DD;
  const float* vsp = vb + (size_t)(s << 6) * DD + f4;

  float4 pv0 = *(const float4*)(vsp + 0 * DD);
  float4 pv1 = *(const float4*)(vsp + 1 * DD);
  float4 pv2 = *(const float4*)(vsp + 2 * DD);
  float4 pv3 = *(const float4*)(vsp + 3 * DD);

  __syncthreads();

  if (wv < 4) {
    float sv[8];
#pragma unroll
    for (int c = 0; c < 8; ++c) sv[c] = alg[wv * ALGS + (c << 6) + lane];
    float mn = sv[0];
#pragma unroll
    for (int c = 1; c < 8; ++c) mn = fminf(mn, sv[c]);
#pragma unroll
    for (int m = 1; m < 64; m <<= 1) mn = fminf(mn, __shfl_xor(mn, m, 64));

    const float CC = 2.8853900817779268f;
    float p[8];
    float sum = 0.f;
#pragma unroll
    for (int c = 0; c < 8; ++c) { p[c] = fast_exp2(CC * (mn - sv[c])); sum += p[c]; }
#pragma unroll
    for (int m = 1; m < 64; m <<= 1) sum += __shfl_xor(sum, m, 64);
    const float inv = fast_rcp(sum);
#pragma unroll
    for (int c = 0; c < 8; ++c) alg[wv * ALGS + (c << 6) + lane] = p[c] * inv;
  }
  __syncthreads();

  {
    const int j = t;
    float4 av = make_float4(alg[j], alg[ALGS + j], alg[2 * ALGS + j], alg[3 * ALGS + j]);
    *(float4*)(out2 + (size_t)(bb * TV + j) * TQ + i0) = av;
  }

  float c4[4][4] = {{0.f,0.f,0.f,0.f},{0.f,0.f,0.f,0.f},
                    {0.f,0.f,0.f,0.f},{0.f,0.f,0.f,0.f}};
  const int jbase = s << 6;
  {
#pragma unroll
    for (int i = 0; i < 4; ++i) {
      float4 ai = *(const float4*)&alg[i * ALGS + jbase];
      c4[i][0] = fmaf(ai.x, pv0.x, c4[i][0]); c4[i][1] = fmaf(ai.x, pv0.y, c4[i][1]);
      c4[i][2] = fmaf(ai.x, pv0.z, c4[i][2]); c4[i][3] = fmaf(ai.x, pv0.w, c4[i][3]);
      c4[i][0] = fmaf(ai.y, pv1.x, c4[i][0]); c4[i][1] = fmaf(ai.y, pv1.y, c4[i][1]);
      c4[i][2] = fmaf(ai.y, pv1.z, c4[i][2]); c4[i][3] = fmaf(ai.y, pv1.w, c4[i][3]);
      c4[i][0] = fmaf(ai.z, pv2.x, c4[i][0]); c4[i][1] = fmaf(ai.z, pv2.y, c4[i][1]);
      c4[i][2] = fmaf(ai.z, pv2.z, c4[i][2]); c4[i][3] = fmaf(ai.z, pv2.w, c4[i][3]);
      c4[i][0] = fmaf(ai.w, pv3.x, c4[i][0]); c4[i][1] = fmaf(ai.w, pv3.y, c4[i][1]);
      c4[i][2] = fmaf(ai.w, pv3.z, c4[i][2]); c4[i][3] = fmaf(ai.w, pv3.w, c4[i][3]);
    }
  }
#pragma unroll 4
  for (int u = 4; u < 64; u += 4) {
    float4 v0 = *(const float4*)(vsp + (size_t)(u + 0) * DD);
    float4 v1 = *(const float4*)(vsp + (size_t)(u + 1) * DD);
    float4 v2 = *(const float4*)(vsp + (size_t)(u + 2) * DD);
    float4 v3 = *(const float4*)(vsp + (size_t)(u + 3) * DD);
#pragma unroll
    for (int i = 0; i < 4; ++i) {
      float4 ai = *(const float4*)&alg[i * ALGS + jbase + u];
      c4[i][0] = fmaf(ai.x, v0.x, c4[i][0]); c4[i][1] = fmaf(ai.x, v0.y, c4[i][1]);
      c4[i][2] = fmaf(ai.x, v0.z, c4[i][2]); c4[i][3] = fmaf(ai.x, v0.w, c4[i][3]);
      c4[i][0] = fmaf(ai.y, v1.x, c4[i][0]); c4[i][1] = fmaf(ai.y, v1.y, c4[i][1]);
      c4[i][2] = fmaf(ai.y, v1.z, c4[i][2]); c4[i][3] = fmaf(ai.y, v1.w, c4[i][3]);
      c4[i][0] = fmaf(ai.z, v2.x, c4[i][0]); c4[i][1] = fmaf(ai.z, v2.y, c4[i][1]);
      c4[i][2] = fmaf(ai.z, v2.z, c4[i][2]); c4[i][3] = fmaf(ai.z, v2.w, c4[i][3]);
      c4[i][0] = fmaf(ai.w, v3.x, c4[i][0]); c4[i][1] = fmaf(ai.w, v3.y, c4[i][1]);
      c4[i][2] = fmaf(ai.w, v3.z, c4[i][2]); c4[i][3] = fmaf(ai.w, v3.w, c4[i][3]);
    }
  }
#pragma unroll
  for (int i = 0; i < 4; ++i)
    *(float4*)&ctxp[s][i][f4] = make_float4(c4[i][0], c4[i][1], c4[i][2], c4[i][3]);
  __syncthreads();

  const float* qg = query + (size_t)(bb * TQ + i0) * DD;
  float* o = out1 + (size_t)(bb * TQ + i0) * (2 * DD);
#pragma unroll
  for (int it = 0; it < 2; ++it) {
    const int slot = t + (it << 9);
    const int ri = slot >> 8;
    const int ff = slot & 255;
    float sum = 0.f;
#pragma unroll
    for (int ss = 0; ss < 8; ++ss) sum += ctxp[ss][ri][ff];
    o[ri * 512 + ff] = sum;
    o[ri * 512 + 256 + ff] = qg[ri * DD + ff];
  }
}

// ---------------------------------------------------------------------------
extern "C" void kernel_launch(void* const* d_in, const int* in_sizes, int n_in,
                              void* d_out, int out_size, void* d_ws, size_t ws_size,
                              hipStream_t stream) {
  const float* query = (const float*)d_in[0];  // [8,256,256]
  const float* value = (const float*)d_in[1];  // [8,512,256]
  const float* W1    = (const float*)d_in[2];  // [256,256]
  const float* b1    = (const float*)d_in[3];  // [256]
  const float* W2    = (const float*)d_in[4];  // [256,256]
  const float* b2    = (const float*)d_in[5];  // [256]

  float* out1 = (float*)d_out;                     // context concat [8,256,512]
  float* out2 = out1 + (size_t)B_ * TQ * 2 * DD;   // alignment_t   [8,512,256]

  float* qp = (float*)d_ws;                        // Eq: 2048*256 floats (2 MB)
  float* vp = qp + (size_t)B_ * TQ * DD;           // Ev: 4096*256 floats (4 MB)
  float* Sp = vp + (size_t)B_ * TV * DD;           // S partials: 2*8*64*2048 floats (8 MB)

  const size_t need = ((size_t)B_ * TQ * DD + (size_t)B_ * TV * DD +
                       (size_t)2 * 8 * 64 * 4 * 512) * sizeof(float);

  const float SC = 2.8853900817779268f;  // 2*log2(e): exp(2x) = exp2(SC*x)

  proj_fused<<<dim3(96, 4), 256, 0, stream>>>(query, value, W1, b1, W2, b2, qp, vp, SC);

  if (ws_size >= need) {
    score_part<<<dim3(1024), 512, 0, stream>>>(qp, vp, Sp);
    ctx_part<<<dim3(1024), 512, 0, stream>>>(Sp, value, query, out1, out2);
  } else {
    attn_mono<<<dim3(B_ * (TQ / 4)), 512, 0, stream>>>(qp, vp, value, query, out1, out2);
  }
}

// Round 7
// 129.937 us; speedup vs baseline: 1.0832x; 1.0832x over previous
//
#include <hip/hip_runtime.h>

#define B_  8
#define TQ  256
#define TV  512
#define DD  256
#define ALGS 520  // alg row stride: quad-write banks {j,j+8,j+16,j+24} -> <=2-way = free

__device__ __forceinline__ float fast_exp2(float x) {
#if __has_builtin(__builtin_amdgcn_exp2f)
  return __builtin_amdgcn_exp2f(x);
#else
  return __exp2f(x);
#endif
}
__device__ __forceinline__ float fast_rcp(float x) {
#if __has_builtin(__builtin_amdgcn_rcpf)
  return __builtin_amdgcn_rcpf(x);
#else
  return 1.0f / x;
#endif
}

// ---------------------------------------------------------------------------
// Fused projections with EXP epilogue (identical to prior rounds — validated):
//   Eq = exp2(SC*(query@W1 + b1)),  Ev = exp2(SC*(value@W2 + b2))
// ---------------------------------------------------------------------------
__global__ __launch_bounds__(256) void proj_fused(
    const float* __restrict__ query, const float* __restrict__ value,
    const float* __restrict__ W1, const float* __restrict__ b1,
    const float* __restrict__ W2, const float* __restrict__ b2,
    float* __restrict__ qp, float* __restrict__ vp, float scale) {
  __shared__ float As[2][32][64];  // [p][k][m ^ sw(k)]
  __shared__ float Bs[2][32][64];  // [p][k][n]
  const int t  = threadIdx.x;
  const int rt = blockIdx.x;
  const int bn = blockIdx.y << 6;

  const float* A; const float* W; const float* bias; float* out; int row0;
  if (rt < 32) { row0 = rt << 6;        A = query; W = W1; bias = b1; out = qp; }
  else         { row0 = (rt - 32) << 6; A = value; W = W2; bias = b2; out = vp; }

  const int tx = t & 15, ty = t >> 4;
  const int aar = t >> 3, aac = (t & 7) << 2;
  const int bbr = t >> 4, bbc = (t & 15) << 2;

  float4 ra[2], rb[2];
#pragma unroll
  for (int it = 0; it < 2; ++it) {
    ra[it] = *(const float4*)(A + (size_t)(row0 + (it << 5) + aar) * DD + aac);
    rb[it] = *(const float4*)(W + (size_t)((it << 4) + bbr) * DD + bn + bbc);
  }
#pragma unroll
  for (int it = 0; it < 2; ++it) {
    const int m = (it << 5) + aar;
#pragma unroll
    for (int c = 0; c < 4; ++c) {
      const int k = aac + c;
      As[0][k][m ^ (((k >> 2) & 7) << 2)] = (&ra[it].x)[c];
    }
    *(float4*)&Bs[0][(it << 4) + bbr][bbc] = rb[it];
  }
  __syncthreads();

  float acc[4][4] = {{0.f,0.f,0.f,0.f},{0.f,0.f,0.f,0.f},
                     {0.f,0.f,0.f,0.f},{0.f,0.f,0.f,0.f}};
  int p = 0;

  for (int k0 = 0; k0 < 256; k0 += 32) {
    const bool more = (k0 + 32) < 256;
    if (more) {
#pragma unroll
      for (int it = 0; it < 2; ++it) {
        ra[it] = *(const float4*)(A + (size_t)(row0 + (it << 5) + aar) * DD + k0 + 32 + aac);
        rb[it] = *(const float4*)(W + (size_t)(k0 + 32 + (it << 4) + bbr) * DD + bn + bbc);
      }
    }
#pragma unroll
    for (int k = 0; k < 32; ++k) {
      float4 aq = *(const float4*)&As[p][k][(ty << 2) ^ (((k >> 2) & 7) << 2)];
      float4 bq = *(const float4*)&Bs[p][k][tx << 2];
      acc[0][0] = fmaf(aq.x, bq.x, acc[0][0]); acc[0][1] = fmaf(aq.x, bq.y, acc[0][1]);
      acc[0][2] = fmaf(aq.x, bq.z, acc[0][2]); acc[0][3] = fmaf(aq.x, bq.w, acc[0][3]);
      acc[1][0] = fmaf(aq.y, bq.x, acc[1][0]); acc[1][1] = fmaf(aq.y, bq.y, acc[1][1]);
      acc[1][2] = fmaf(aq.y, bq.z, acc[1][2]); acc[1][3] = fmaf(aq.y, bq.w, acc[1][3]);
      acc[2][0] = fmaf(aq.z, bq.x, acc[2][0]); acc[2][1] = fmaf(aq.z, bq.y, acc[2][1]);
      acc[2][2] = fmaf(aq.z, bq.z, acc[2][2]); acc[2][3] = fmaf(aq.z, bq.w, acc[2][3]);
      acc[3][0] = fmaf(aq.w, bq.x, acc[3][0]); acc[3][1] = fmaf(aq.w, bq.y, acc[3][1]);
      acc[3][2] = fmaf(aq.w, bq.z, acc[3][2]); acc[3][3] = fmaf(aq.w, bq.w, acc[3][3]);
    }
    if (more) {
      const int q = p ^ 1;
#pragma unroll
      for (int it = 0; it < 2; ++it) {
        const int m = (it << 5) + aar;
#pragma unroll
        for (int c = 0; c < 4; ++c) {
          const int k = aac + c;
          As[q][k][m ^ (((k >> 2) & 7) << 2)] = (&ra[it].x)[c];
        }
        *(float4*)&Bs[q][(it << 4) + bbr][bbc] = rb[it];
      }
      __syncthreads();
      p = q;
    }
  }

  float4 bvv = *(const float4*)&bias[bn + (tx << 2)];
#pragma unroll
  for (int r = 0; r < 4; ++r) {
    float4 o;
    o.x = fast_exp2(scale * (acc[r][0] + bvv.x));
    o.y = fast_exp2(scale * (acc[r][1] + bvv.y));
    o.z = fast_exp2(scale * (acc[r][2] + bvv.z));
    o.w = fast_exp2(scale * (acc[r][3] + bvv.w));
    *(float4*)(out + (size_t)(row0 + (ty << 2) + r) * DD + bn + (tx << 2)) = o;
  }
}

// ---------------------------------------------------------------------------
// Fused score + softmax + context + concat + transposed alignment.
// THIS ROUND: occupancy via LDS shrink, NOT grid growth (R4) or kernel
// splits (R5/R6 — both regressed). Same 512-block grid, same traffic, same
// single launch as the validated R2 monolith (attn 46.6 us); the only
// structural change is the context strip-reduction done in TWO sequential
// feature-halves (ctxp[8][4][128] = 16 KB instead of 32 KB), dropping LDS
// 45.5 -> 28.5 KB/block => 4 blocks/CU, 32 waves/CU (was 2 blocks, 16).
// __launch_bounds__(512, 8); R2 compiled at 44 VGPR so the 64-cap is safe.
// Score loop / butterfly / softmax / context fma loop / pv prefetch = R2
// verbatim. Cost: +3 epilogue barriers (negligible).
// ---------------------------------------------------------------------------
__global__ __launch_bounds__(512, 8) void attn_mono(
    const float* __restrict__ qp, const float* __restrict__ vp,
    const float* __restrict__ value, const float* __restrict__ query,
    float* __restrict__ out1, float* __restrict__ out2) {
  __shared__ float qs[4 * 256];        // Eq rows, 4 KB
  __shared__ float alg[4 * ALGS];      // raw S then alignment, 8.3 KB
  __shared__ float ctxp[8][4][128];    // context strip partials, 16 KB (half)

  const int t    = threadIdx.x;
  const int lane = t & 63;
  const int wv   = t >> 6;        // 0..7
  const int jj   = lane >> 2;     // 0..15: row within wave's 16-row group
  const int dq   = lane & 3;      // d-quarter phase
  const int bb   = blockIdx.x & 7;          // batch -> XCD locality
  const int i0   = (blockIdx.x >> 3) << 2;  // first of 4 q-rows

  const float* vpb = vp + (size_t)bb * TV * DD;
  const float* qb  = qp + (size_t)(bb * TQ + i0) * DD;

  // stage 4 Eq rows into LDS (coalesced, all 512 threads, float2 each)
  {
    const int qi = t >> 7, qc = (t & 127) << 1;
    *(float2*)&qs[qi * 256 + qc] = *(const float2*)(qb + (size_t)qi * DD + qc);
  }
  __syncthreads();

  // per-lane Ev row bases: j(jg) = jg*128 + wv*16 + jj
  const int jb = (wv << 4) + jj;
  const float* vr0 = vpb + (size_t)jb * DD + (dq << 2);
  const float* vr1 = vr0 + 128 * DD;
  const float* vr2 = vr0 + 256 * DD;
  const float* vr3 = vr0 + 384 * DD;
  const float* qlane = qs + (dq << 2);

  float acc[4][4] = {{0.f,0.f,0.f,0.f},{0.f,0.f,0.f,0.f},
                     {0.f,0.f,0.f,0.f},{0.f,0.f,0.f,0.f}};

#pragma unroll 4
  for (int k = 0; k < 16; ++k) {
    const int doff = k << 4;  // 16 floats per k-step
    float4 q0 = *(const float4*)(qlane + 0 * 256 + doff);
    float4 q1 = *(const float4*)(qlane + 1 * 256 + doff);
    float4 q2 = *(const float4*)(qlane + 2 * 256 + doff);
    float4 q3 = *(const float4*)(qlane + 3 * 256 + doff);
#pragma unroll
    for (int jg = 0; jg < 4; ++jg) {
      const float* vrp = (jg == 0) ? vr0 : (jg == 1) ? vr1 : (jg == 2) ? vr2 : vr3;
      float4 v4 = *(const float4*)(vrp + doff);
#pragma unroll
      for (int i = 0; i < 4; ++i) {
        const float4 q4 = (i == 0) ? q0 : (i == 1) ? q1 : (i == 2) ? q2 : q3;
        float a = q4.x * v4.x, b = q4.y * v4.y;
        float c = q4.z * v4.z, d = q4.w * v4.w;
        float sab = a + b,  scd = c + d;
        float Q1 = fmaf(a, b, sab + 1.f);   // (1+a)(1+b)
        float Q2 = fmaf(c, d, scd + 1.f);   // (1+c)(1+d)
        float N  = fmaf(scd + 2.f, Q1, (sab + 2.f) * Q2);
        acc[i][jg] = fmaf(N, fast_rcp(Q1 * Q2), acc[i][jg]);
      }
    }
  }

  // quad butterfly (once): combine the 4 d-quarter partials within each jj
#pragma unroll
  for (int i = 0; i < 4; ++i)
#pragma unroll
    for (int jg = 0; jg < 4; ++jg) {
      acc[i][jg] += __shfl_xor(acc[i][jg], 1, 64);
      acc[i][jg] += __shfl_xor(acc[i][jg], 2, 64);
    }
  // lane writes the i = dq slice (banks <=2-way with ALGS=520)
#pragma unroll
  for (int jg = 0; jg < 4; ++jg) {
    float x = (dq == 0) ? acc[0][jg] : (dq == 1) ? acc[1][jg]
            : (dq == 2) ? acc[2][jg] : acc[3][jg];
    alg[dq * ALGS + (jg << 7) + jb] = x;
  }

  // ---- context addressing + first-chunk prefetch (independent of softmax;
  //      latency hides under softmax + barriers) ----
  const int f4 = (t & 63) << 2;   // feature base: 0,4,...,252
  const int s  = t >> 6;          // j-strip: [s*64, s*64+64)
  const float* vb  = value + (size_t)bb * TV * DD;
  const float* vsp = vb + (size_t)(s << 6) * DD + f4;

  float4 pv0 = *(const float4*)(vsp + 0 * DD);
  float4 pv1 = *(const float4*)(vsp + 1 * DD);
  float4 pv2 = *(const float4*)(vsp + 2 * DD);
  float4 pv3 = *(const float4*)(vsp + 3 * DD);

  __syncthreads();

  // ---- softmax over j: wave wv (<4) owns row wv exclusively ----
  // score = 256 - 2*S -> max(score) <-> min(S); w = exp2(CC*(Smin - S))
  if (wv < 4) {
    float sv[8];
#pragma unroll
    for (int c = 0; c < 8; ++c) sv[c] = alg[wv * ALGS + (c << 6) + lane];
    float mn = sv[0];
#pragma unroll
    for (int c = 1; c < 8; ++c) mn = fminf(mn, sv[c]);
#pragma unroll
    for (int m = 1; m < 64; m <<= 1) mn = fminf(mn, __shfl_xor(mn, m, 64));

    const float CC = 2.8853900817779268f;  // 2*log2(e)
    float p[8];
    float sum = 0.f;
#pragma unroll
    for (int c = 0; c < 8; ++c) { p[c] = fast_exp2(CC * (mn - sv[c])); sum += p[c]; }
#pragma unroll
    for (int m = 1; m < 64; m <<= 1) sum += __shfl_xor(sum, m, 64);
    const float inv = fast_rcp(sum);
#pragma unroll
    for (int c = 0; c < 8; ++c) alg[wv * ALGS + (c << 6) + lane] = p[c] * inv;
  }
  __syncthreads();

  // ---- alignment_t write: out2[b][j][i0..i0+3], one float4 per thread ----
  {
    const int j = t;  // 0..511
    float4 av = make_float4(alg[j], alg[ALGS + j], alg[2 * ALGS + j], alg[3 * ALGS + j]);
    *(float4*)(out2 + (size_t)(bb * TV + j) * TQ + i0) = av;
  }

  // ---- context: thread (s, f4) does 4 rows x 4 features over 64 j ----
  float c4[4][4] = {{0.f,0.f,0.f,0.f},{0.f,0.f,0.f,0.f},
                    {0.f,0.f,0.f,0.f},{0.f,0.f,0.f,0.f}};
  const int jbase = s << 6;
  {
    // u = 0 chunk from prefetched registers
#pragma unroll
    for (int i = 0; i < 4; ++i) {
      float4 ai = *(const float4*)&alg[i * ALGS + jbase];
      c4[i][0] = fmaf(ai.x, pv0.x, c4[i][0]); c4[i][1] = fmaf(ai.x, pv0.y, c4[i][1]);
      c4[i][2] = fmaf(ai.x, pv0.z, c4[i][2]); c4[i][3] = fmaf(ai.x, pv0.w, c4[i][3]);
      c4[i][0] = fmaf(ai.y, pv1.x, c4[i][0]); c4[i][1] = fmaf(ai.y, pv1.y, c4[i][1]);
      c4[i][2] = fmaf(ai.y, pv1.z, c4[i][2]); c4[i][3] = fmaf(ai.y, pv1.w, c4[i][3]);
      c4[i][0] = fmaf(ai.z, pv2.x, c4[i][0]); c4[i][1] = fmaf(ai.z, pv2.y, c4[i][1]);
      c4[i][2] = fmaf(ai.z, pv2.z, c4[i][2]); c4[i][3] = fmaf(ai.z, pv2.w, c4[i][3]);
      c4[i][0] = fmaf(ai.w, pv3.x, c4[i][0]); c4[i][1] = fmaf(ai.w, pv3.y, c4[i][1]);
      c4[i][2] = fmaf(ai.w, pv3.z, c4[i][2]); c4[i][3] = fmaf(ai.w, pv3.w, c4[i][3]);
    }
  }
#pragma unroll 4
  for (int u = 4; u < 64; u += 4) {
    float4 v0 = *(const float4*)(vsp + (size_t)(u + 0) * DD);
    float4 v1 = *(const float4*)(vsp + (size_t)(u + 1) * DD);
    float4 v2 = *(const float4*)(vsp + (size_t)(u + 2) * DD);
    float4 v3 = *(const float4*)(vsp + (size_t)(u + 3) * DD);
#pragma unroll
    for (int i = 0; i < 4; ++i) {
      float4 ai = *(const float4*)&alg[i * ALGS + jbase + u];
      c4[i][0] = fmaf(ai.x, v0.x, c4[i][0]); c4[i][1] = fmaf(ai.x, v0.y, c4[i][1]);
      c4[i][2] = fmaf(ai.x, v0.z, c4[i][2]); c4[i][3] = fmaf(ai.x, v0.w, c4[i][3]);
      c4[i][0] = fmaf(ai.y, v1.x, c4[i][0]); c4[i][1] = fmaf(ai.y, v1.y, c4[i][1]);
      c4[i][2] = fmaf(ai.y, v1.z, c4[i][2]); c4[i][3] = fmaf(ai.y, v1.w, c4[i][3]);
      c4[i][0] = fmaf(ai.z, v2.x, c4[i][0]); c4[i][1] = fmaf(ai.z, v2.y, c4[i][1]);
      c4[i][2] = fmaf(ai.z, v2.z, c4[i][2]); c4[i][3] = fmaf(ai.z, v2.w, c4[i][3]);
      c4[i][0] = fmaf(ai.w, v3.x, c4[i][0]); c4[i][1] = fmaf(ai.w, v3.y, c4[i][1]);
      c4[i][2] = fmaf(ai.w, v3.z, c4[i][2]); c4[i][3] = fmaf(ai.w, v3.w, c4[i][3]);
    }
  }

  // ---- TWO-PASS strip reduction + concat output (halved ctxp LDS) ----
  // half h covers features [h*128, h*128+128). Threads whose f4 is in the
  // half store partials; all threads then reduce 8 strips and write.
  const float* qg = query + (size_t)(bb * TQ + i0) * DD;
  float* o = out1 + (size_t)(bb * TQ + i0) * (2 * DD);
#pragma unroll
  for (int h = 0; h < 2; ++h) {
    if ((f4 >> 7) == h) {
      const int fi = f4 & 127;
#pragma unroll
      for (int i = 0; i < 4; ++i)
        *(float4*)&ctxp[s][i][fi] = make_float4(c4[i][0], c4[i][1], c4[i][2], c4[i][3]);
    }
    __syncthreads();
    {
      const int ri = t >> 7;        // row 0..3
      const int ff = t & 127;       // feature within half
      float sum = 0.f;
#pragma unroll
      for (int ss = 0; ss < 8; ++ss) sum += ctxp[ss][ri][ff];
      o[ri * 512 + (h << 7) + ff] = sum;
      o[ri * 512 + 256 + (h << 7) + ff] = qg[ri * DD + (h << 7) + ff];
    }
    if (h == 0) __syncthreads();  // protect ctxp reuse (write-after-read)
  }
}

// ---------------------------------------------------------------------------
extern "C" void kernel_launch(void* const* d_in, const int* in_sizes, int n_in,
                              void* d_out, int out_size, void* d_ws, size_t ws_size,
                              hipStream_t stream) {
  const float* query = (const float*)d_in[0];  // [8,256,256]
  const float* value = (const float*)d_in[1];  // [8,512,256]
  const float* W1    = (const float*)d_in[2];  // [256,256]
  const float* b1    = (const float*)d_in[3];  // [256]
  const float* W2    = (const float*)d_in[4];  // [256,256]
  const float* b2    = (const float*)d_in[5];  // [256]

  float* out1 = (float*)d_out;                     // context concat [8,256,512]
  float* out2 = out1 + (size_t)B_ * TQ * 2 * DD;   // alignment_t   [8,512,256]

  float* qp = (float*)d_ws;                        // Eq: 2048*256 floats
  float* vp = qp + (size_t)B_ * TQ * DD;           // Ev: 4096*256 floats

  const float SC = 2.8853900817779268f;  // 2*log2(e): exp(2x) = exp2(SC*x)

  proj_fused<<<dim3(96, 4), 256, 0, stream>>>(query, value, W1, b1, W2, b2, qp, vp, SC);
  attn_mono<<<dim3(B_ * (TQ / 4)), 512, 0, stream>>>(qp, vp, value, query, out1, out2);
}

// Round 8
// 128.307 us; speedup vs baseline: 1.0970x; 1.0127x over previous
//
#include <hip/hip_runtime.h>

#define B_  8
#define TQ  256
#define TV  512
#define DD  256
#define ALGS 520  // alg row stride: quad-write banks {j,j+8,j+16,j+24} -> <=2-way = free

__device__ __forceinline__ float fast_exp2(float x) {
#if __has_builtin(__builtin_amdgcn_exp2f)
  return __builtin_amdgcn_exp2f(x);
#else
  return __exp2f(x);
#endif
}
__device__ __forceinline__ float fast_rcp(float x) {
#if __has_builtin(__builtin_amdgcn_rcpf)
  return __builtin_amdgcn_rcpf(x);
#else
  return 1.0f / x;
#endif
}

// ---------------------------------------------------------------------------
// Fused projections with EXP epilogue (identical to prior rounds — validated):
//   Eq = exp2(SC*(query@W1 + b1)),  Ev = exp2(SC*(value@W2 + b2))
// NOTE (R7 accounting): proj ≈ 40 us vs ~5 us ideal — next major target once
// attn drops enough to expose it in the top-5 profile.
// ---------------------------------------------------------------------------
__global__ __launch_bounds__(256) void proj_fused(
    const float* __restrict__ query, const float* __restrict__ value,
    const float* __restrict__ W1, const float* __restrict__ b1,
    const float* __restrict__ W2, const float* __restrict__ b2,
    float* __restrict__ qp, float* __restrict__ vp, float scale) {
  __shared__ float As[2][32][64];  // [p][k][m ^ sw(k)]
  __shared__ float Bs[2][32][64];  // [p][k][n]
  const int t  = threadIdx.x;
  const int rt = blockIdx.x;
  const int bn = blockIdx.y << 6;

  const float* A; const float* W; const float* bias; float* out; int row0;
  if (rt < 32) { row0 = rt << 6;        A = query; W = W1; bias = b1; out = qp; }
  else         { row0 = (rt - 32) << 6; A = value; W = W2; bias = b2; out = vp; }

  const int tx = t & 15, ty = t >> 4;
  const int aar = t >> 3, aac = (t & 7) << 2;
  const int bbr = t >> 4, bbc = (t & 15) << 2;

  float4 ra[2], rb[2];
#pragma unroll
  for (int it = 0; it < 2; ++it) {
    ra[it] = *(const float4*)(A + (size_t)(row0 + (it << 5) + aar) * DD + aac);
    rb[it] = *(const float4*)(W + (size_t)((it << 4) + bbr) * DD + bn + bbc);
  }
#pragma unroll
  for (int it = 0; it < 2; ++it) {
    const int m = (it << 5) + aar;
#pragma unroll
    for (int c = 0; c < 4; ++c) {
      const int k = aac + c;
      As[0][k][m ^ (((k >> 2) & 7) << 2)] = (&ra[it].x)[c];
    }
    *(float4*)&Bs[0][(it << 4) + bbr][bbc] = rb[it];
  }
  __syncthreads();

  float acc[4][4] = {{0.f,0.f,0.f,0.f},{0.f,0.f,0.f,0.f},
                     {0.f,0.f,0.f,0.f},{0.f,0.f,0.f,0.f}};
  int p = 0;

  for (int k0 = 0; k0 < 256; k0 += 32) {
    const bool more = (k0 + 32) < 256;
    if (more) {
#pragma unroll
      for (int it = 0; it < 2; ++it) {
        ra[it] = *(const float4*)(A + (size_t)(row0 + (it << 5) + aar) * DD + k0 + 32 + aac);
        rb[it] = *(const float4*)(W + (size_t)(k0 + 32 + (it << 4) + bbr) * DD + bn + bbc);
      }
    }
#pragma unroll
    for (int k = 0; k < 32; ++k) {
      float4 aq = *(const float4*)&As[p][k][(ty << 2) ^ (((k >> 2) & 7) << 2)];
      float4 bq = *(const float4*)&Bs[p][k][tx << 2];
      acc[0][0] = fmaf(aq.x, bq.x, acc[0][0]); acc[0][1] = fmaf(aq.x, bq.y, acc[0][1]);
      acc[0][2] = fmaf(aq.x, bq.z, acc[0][2]); acc[0][3] = fmaf(aq.x, bq.w, acc[0][3]);
      acc[1][0] = fmaf(aq.y, bq.x, acc[1][0]); acc[1][1] = fmaf(aq.y, bq.y, acc[1][1]);
      acc[1][2] = fmaf(aq.y, bq.z, acc[1][2]); acc[1][3] = fmaf(aq.y, bq.w, acc[1][3]);
      acc[2][0] = fmaf(aq.z, bq.x, acc[2][0]); acc[2][1] = fmaf(aq.z, bq.y, acc[2][1]);
      acc[2][2] = fmaf(aq.z, bq.z, acc[2][2]); acc[2][3] = fmaf(aq.z, bq.w, acc[2][3]);
      acc[3][0] = fmaf(aq.w, bq.x, acc[3][0]); acc[3][1] = fmaf(aq.w, bq.y, acc[3][1]);
      acc[3][2] = fmaf(aq.w, bq.z, acc[3][2]); acc[3][3] = fmaf(aq.w, bq.w, acc[3][3]);
    }
    if (more) {
      const int q = p ^ 1;
#pragma unroll
      for (int it = 0; it < 2; ++it) {
        const int m = (it << 5) + aar;
#pragma unroll
        for (int c = 0; c < 4; ++c) {
          const int k = aac + c;
          As[q][k][m ^ (((k >> 2) & 7) << 2)] = (&ra[it].x)[c];
        }
        *(float4*)&Bs[q][(it << 4) + bbr][bbc] = rb[it];
      }
      __syncthreads();
      p = q;
    }
  }

  float4 bvv = *(const float4*)&bias[bn + (tx << 2)];
#pragma unroll
  for (int r = 0; r < 4; ++r) {
    float4 o;
    o.x = fast_exp2(scale * (acc[r][0] + bvv.x));
    o.y = fast_exp2(scale * (acc[r][1] + bvv.y));
    o.z = fast_exp2(scale * (acc[r][2] + bvv.z));
    o.w = fast_exp2(scale * (acc[r][3] + bvv.w));
    *(float4*)(out + (size_t)(row0 + (ty << 2) + r) * DD + bn + (tx << 2)) = o;
  }
}

// ---------------------------------------------------------------------------
// Fused score + softmax + context + concat + transposed alignment.
// THIS ROUND: true occupancy test. Same 512-block grid, same traffic, same
// single launch — but 1024 threads (16 waves) per block. Wave w: row-group
// wv = w&7 (16 Ev rows x 4 jg), d-half dh = w>>3 (8 k-steps over
// [dh*128, dh*128+128)). Each (row, d-half) is read by exactly one wave ->
// per-block Ev bytes UNCHANGED (R4's trap avoided). d-halves combined by one
// LDS add (numerically = R5's validated slo+shi split). Context: 16 strips
// x 32 j. 2 blocks/CU x 16 waves = 32 waves/CU (100% cap, was 16).
// LDS 44.1 KB x 2 = 88 KB < 160. __launch_bounds__(1024,8) caps VGPR at 64
// (R7 measured 32). Score body / butterfly / softmax math = R2 verbatim.
// ---------------------------------------------------------------------------
__global__ __launch_bounds__(1024, 8) void attn_mono(
    const float* __restrict__ qp, const float* __restrict__ vp,
    const float* __restrict__ value, const float* __restrict__ query,
    float* __restrict__ out1, float* __restrict__ out2) {
  __shared__ float qs[4 * 256];        // Eq rows, 4 KB
  __shared__ float alg[4 * ALGS];      // raw S then alignment, 8.3 KB
  __shared__ float ctxp[16][4][128];   // context strip partials, 32 KB

  const int t    = threadIdx.x;        // 0..1023
  const int lane = t & 63;
  const int w    = t >> 6;        // wave 0..15
  const int wv   = w & 7;         // row-group wave
  const int dh   = w >> 3;        // d-half 0/1
  const int jj   = lane >> 2;     // 0..15: row within wave's 16-row group
  const int dq   = lane & 3;      // d-quarter phase
  const int bb   = blockIdx.x & 7;          // batch -> XCD locality
  const int i0   = (blockIdx.x >> 3) << 2;  // first of 4 q-rows

  const float* vpb = vp + (size_t)bb * TV * DD;
  const float* qb  = qp + (size_t)(bb * TQ + i0) * DD;

  // stage 4 Eq rows into LDS (coalesced, 1 float per thread)
  qs[t] = qb[(size_t)(t >> 8) * DD + (t & 255)];
  __syncthreads();

  // per-lane Ev row bases: j(jg) = jg*128 + wv*16 + jj; d-slice = dh half
  const int jb = (wv << 4) + jj;
  const int d0 = dh << 7;
  const float* vr0 = vpb + (size_t)jb * DD + d0 + (dq << 2);
  const float* vr1 = vr0 + 128 * DD;
  const float* vr2 = vr0 + 256 * DD;
  const float* vr3 = vr0 + 384 * DD;
  const float* qlane = qs + d0 + (dq << 2);

  float acc[4][4] = {{0.f,0.f,0.f,0.f},{0.f,0.f,0.f,0.f},
                     {0.f,0.f,0.f,0.f},{0.f,0.f,0.f,0.f}};

#pragma unroll 4
  for (int k = 0; k < 8; ++k) {
    const int doff = k << 4;  // 16 floats per k-step within the half
    float4 q0 = *(const float4*)(qlane + 0 * 256 + doff);
    float4 q1 = *(const float4*)(qlane + 1 * 256 + doff);
    float4 q2 = *(const float4*)(qlane + 2 * 256 + doff);
    float4 q3 = *(const float4*)(qlane + 3 * 256 + doff);
#pragma unroll
    for (int jg = 0; jg < 4; ++jg) {
      const float* vrp = (jg == 0) ? vr0 : (jg == 1) ? vr1 : (jg == 2) ? vr2 : vr3;
      float4 v4 = *(const float4*)(vrp + doff);
#pragma unroll
      for (int i = 0; i < 4; ++i) {
        const float4 q4 = (i == 0) ? q0 : (i == 1) ? q1 : (i == 2) ? q2 : q3;
        float a = q4.x * v4.x, b = q4.y * v4.y;
        float c = q4.z * v4.z, d = q4.w * v4.w;
        float sab = a + b,  scd = c + d;
        float Q1 = fmaf(a, b, sab + 1.f);   // (1+a)(1+b)
        float Q2 = fmaf(c, d, scd + 1.f);   // (1+c)(1+d)
        float N  = fmaf(scd + 2.f, Q1, (sab + 2.f) * Q2);
        acc[i][jg] = fmaf(N, fast_rcp(Q1 * Q2), acc[i][jg]);
      }
    }
  }

  // quad butterfly (once): combine the 4 d-quarter partials within each jj
#pragma unroll
  for (int i = 0; i < 4; ++i)
#pragma unroll
    for (int jg = 0; jg < 4; ++jg) {
      acc[i][jg] += __shfl_xor(acc[i][jg], 1, 64);
      acc[i][jg] += __shfl_xor(acc[i][jg], 2, 64);
    }

  // select the i = dq slice per lane (compile-time indices)
  float xh[4];
#pragma unroll
  for (int jg = 0; jg < 4; ++jg)
    xh[jg] = (dq == 0) ? acc[0][jg] : (dq == 1) ? acc[1][jg]
           : (dq == 2) ? acc[2][jg] : acc[3][jg];

  // d-half 0 writes alg; barrier; d-half 1 adds (one writer per location)
  if (dh == 0) {
#pragma unroll
    for (int jg = 0; jg < 4; ++jg) alg[dq * ALGS + (jg << 7) + jb] = xh[jg];
  }

  // ---- context addressing + first-chunk prefetch (independent of softmax;
  //      issue before the combine barriers so L2 latency hides) ----
  const int f4 = (t & 63) << 2;   // feature base: 0,4,...,252
  const int s  = t >> 6;          // j-strip 0..15: [s*32, s*32+32)
  const float* vb  = value + (size_t)bb * TV * DD;
  const float* vsp = vb + (size_t)(s << 5) * DD + f4;

  float4 pv0 = *(const float4*)(vsp + 0 * DD);
  float4 pv1 = *(const float4*)(vsp + 1 * DD);
  float4 pv2 = *(const float4*)(vsp + 2 * DD);
  float4 pv3 = *(const float4*)(vsp + 3 * DD);

  __syncthreads();
  if (dh == 1) {
#pragma unroll
    for (int jg = 0; jg < 4; ++jg) alg[dq * ALGS + (jg << 7) + jb] += xh[jg];
  }
  __syncthreads();

  // ---- softmax over j: wave w (<4) owns row w exclusively ----
  // score = 256 - 2*S -> max(score) <-> min(S); w = exp2(CC*(Smin - S))
  if (w < 4) {
    float sv[8];
#pragma unroll
    for (int c = 0; c < 8; ++c) sv[c] = alg[w * ALGS + (c << 6) + lane];
    float mn = sv[0];
#pragma unroll
    for (int c = 1; c < 8; ++c) mn = fminf(mn, sv[c]);
#pragma unroll
    for (int m = 1; m < 64; m <<= 1) mn = fminf(mn, __shfl_xor(mn, m, 64));

    const float CC = 2.8853900817779268f;  // 2*log2(e)
    float p[8];
    float sum = 0.f;
#pragma unroll
    for (int c = 0; c < 8; ++c) { p[c] = fast_exp2(CC * (mn - sv[c])); sum += p[c]; }
#pragma unroll
    for (int m = 1; m < 64; m <<= 1) sum += __shfl_xor(sum, m, 64);
    const float inv = fast_rcp(sum);
#pragma unroll
    for (int c = 0; c < 8; ++c) alg[w * ALGS + (c << 6) + lane] = p[c] * inv;
  }
  __syncthreads();

  // ---- alignment_t write: out2[b][j][i0..i0+3], one float4, t<512 ----
  if (t < 512) {
    const int j = t;
    float4 av = make_float4(alg[j], alg[ALGS + j], alg[2 * ALGS + j], alg[3 * ALGS + j]);
    *(float4*)(out2 + (size_t)(bb * TV + j) * TQ + i0) = av;
  }

  // ---- context: thread (s, f4) does 4 rows x 4 features over 32 j ----
  float c4[4][4] = {{0.f,0.f,0.f,0.f},{0.f,0.f,0.f,0.f},
                    {0.f,0.f,0.f,0.f},{0.f,0.f,0.f,0.f}};
  const int jbase = s << 5;
  {
    // u = 0 chunk from prefetched registers
#pragma unroll
    for (int i = 0; i < 4; ++i) {
      float4 ai = *(const float4*)&alg[i * ALGS + jbase];
      c4[i][0] = fmaf(ai.x, pv0.x, c4[i][0]); c4[i][1] = fmaf(ai.x, pv0.y, c4[i][1]);
      c4[i][2] = fmaf(ai.x, pv0.z, c4[i][2]); c4[i][3] = fmaf(ai.x, pv0.w, c4[i][3]);
      c4[i][0] = fmaf(ai.y, pv1.x, c4[i][0]); c4[i][1] = fmaf(ai.y, pv1.y, c4[i][1]);
      c4[i][2] = fmaf(ai.y, pv1.z, c4[i][2]); c4[i][3] = fmaf(ai.y, pv1.w, c4[i][3]);
      c4[i][0] = fmaf(ai.z, pv2.x, c4[i][0]); c4[i][1] = fmaf(ai.z, pv2.y, c4[i][1]);
      c4[i][2] = fmaf(ai.z, pv2.z, c4[i][2]); c4[i][3] = fmaf(ai.z, pv2.w, c4[i][3]);
      c4[i][0] = fmaf(ai.w, pv3.x, c4[i][0]); c4[i][1] = fmaf(ai.w, pv3.y, c4[i][1]);
      c4[i][2] = fmaf(ai.w, pv3.z, c4[i][2]); c4[i][3] = fmaf(ai.w, pv3.w, c4[i][3]);
    }
  }
#pragma unroll
  for (int u = 4; u < 32; u += 4) {
    float4 v0 = *(const float4*)(vsp + (size_t)(u + 0) * DD);
    float4 v1 = *(const float4*)(vsp + (size_t)(u + 1) * DD);
    float4 v2 = *(const float4*)(vsp + (size_t)(u + 2) * DD);
    float4 v3 = *(const float4*)(vsp + (size_t)(u + 3) * DD);
#pragma unroll
    for (int i = 0; i < 4; ++i) {
      float4 ai = *(const float4*)&alg[i * ALGS + jbase + u];
      c4[i][0] = fmaf(ai.x, v0.x, c4[i][0]); c4[i][1] = fmaf(ai.x, v0.y, c4[i][1]);
      c4[i][2] = fmaf(ai.x, v0.z, c4[i][2]); c4[i][3] = fmaf(ai.x, v0.w, c4[i][3]);
      c4[i][0] = fmaf(ai.y, v1.x, c4[i][0]); c4[i][1] = fmaf(ai.y, v1.y, c4[i][1]);
      c4[i][2] = fmaf(ai.y, v1.z, c4[i][2]); c4[i][3] = fmaf(ai.y, v1.w, c4[i][3]);
      c4[i][0] = fmaf(ai.z, v2.x, c4[i][0]); c4[i][1] = fmaf(ai.z, v2.y, c4[i][1]);
      c4[i][2] = fmaf(ai.z, v2.z, c4[i][2]); c4[i][3] = fmaf(ai.z, v2.w, c4[i][3]);
      c4[i][0] = fmaf(ai.w, v3.x, c4[i][0]); c4[i][1] = fmaf(ai.w, v3.y, c4[i][1]);
      c4[i][2] = fmaf(ai.w, v3.z, c4[i][2]); c4[i][3] = fmaf(ai.w, v3.w, c4[i][3]);
    }
  }

  // ---- TWO-PASS strip reduction + concat output (16 strips, half ctxp) ----
  const float* qg = query + (size_t)(bb * TQ + i0) * DD;
  float* o = out1 + (size_t)(bb * TQ + i0) * (2 * DD);
#pragma unroll
  for (int h = 0; h < 2; ++h) {
    if ((f4 >> 7) == h) {
      const int fi = f4 & 127;
#pragma unroll
      for (int i = 0; i < 4; ++i)
        *(float4*)&ctxp[s][i][fi] = make_float4(c4[i][0], c4[i][1], c4[i][2], c4[i][3]);
    }
    __syncthreads();
    if (t < 512) {
      const int ri = t >> 7;        // row 0..3
      const int ff = t & 127;       // feature within half
      float sum = 0.f;
#pragma unroll
      for (int ss = 0; ss < 16; ++ss) sum += ctxp[ss][ri][ff];
      o[ri * 512 + (h << 7) + ff] = sum;
      o[ri * 512 + 256 + (h << 7) + ff] = qg[ri * DD + (h << 7) + ff];
    }
    if (h == 0) __syncthreads();  // protect ctxp reuse (write-after-read)
  }
}

// ---------------------------------------------------------------------------
extern "C" void kernel_launch(void* const* d_in, const int* in_sizes, int n_in,
                              void* d_out, int out_size, void* d_ws, size_t ws_size,
                              hipStream_t stream) {
  const float* query = (const float*)d_in[0];  // [8,256,256]
  const float* value = (const float*)d_in[1];  // [8,512,256]
  const float* W1    = (const float*)d_in[2];  // [256,256]
  const float* b1    = (const float*)d_in[3];  // [256]
  const float* W2    = (const float*)d_in[4];  // [256,256]
  const float* b2    = (const float*)d_in[5];  // [256]

  float* out1 = (float*)d_out;                     // context concat [8,256,512]
  float* out2 = out1 + (size_t)B_ * TQ * 2 * DD;   // alignment_t   [8,512,256]

  float* qp = (float*)d_ws;                        // Eq: 2048*256 floats
  float* vp = qp + (size_t)B_ * TQ * DD;           // Ev: 4096*256 floats

  const float SC = 2.8853900817779268f;  // 2*log2(e): exp(2x) = exp2(SC*x)

  proj_fused<<<dim3(96, 4), 256, 0, stream>>>(query, value, W1, b1, W2, b2, qp, vp, SC);
  attn_mono<<<dim3(B_ * (TQ / 4)), 1024, 0, stream>>>(qp, vp, value, query, out1, out2);
}

// Round 9
// 128.164 us; speedup vs baseline: 1.0982x; 1.0011x over previous
//
#include <hip/hip_runtime.h>

#define B_  8
#define TQ  256
#define TV  512
#define DD  256
#define ALGS 520  // alg row stride: quad-write banks {j,j+8,j+16,j+24} -> <=2-way = free

__device__ __forceinline__ float fast_exp2(float x) {
#if __has_builtin(__builtin_amdgcn_exp2f)
  return __builtin_amdgcn_exp2f(x);
#else
  return __exp2f(x);
#endif
}
__device__ __forceinline__ float fast_rcp(float x) {
#if __has_builtin(__builtin_amdgcn_rcpf)
  return __builtin_amdgcn_rcpf(x);
#else
  return 1.0f / x;
#endif
}

// ---------------------------------------------------------------------------
// Fused projections with EXP epilogue. THIS ROUND: 512 threads/block
// (4 rows x 2 cols per thread, was 256 thr x 4x4). Same 64x64 tiles, same
// LDS layout/swizzle, same k-summation order (bitwise-identical outputs).
// Waves/CU: 6 -> 12 (proj was the occupancy-starved kernel: 384 blocks =
// 1.5 blocks/CU; measured ~37-40 us vs ~5 us ideal).
// ---------------------------------------------------------------------------
__global__ __launch_bounds__(512) void proj_fused(
    const float* __restrict__ query, const float* __restrict__ value,
    const float* __restrict__ W1, const float* __restrict__ b1,
    const float* __restrict__ W2, const float* __restrict__ b2,
    float* __restrict__ qp, float* __restrict__ vp, float scale) {
  __shared__ float As[2][32][64];  // [p][k][m ^ sw(k)]
  __shared__ float Bs[2][32][64];  // [p][k][n]
  const int t  = threadIdx.x;
  const int rt = blockIdx.x;
  const int bn = blockIdx.y << 6;

  const float* A; const float* W; const float* bias; float* out; int row0;
  if (rt < 32) { row0 = rt << 6;        A = query; W = W1; bias = b1; out = qp; }
  else         { row0 = (rt - 32) << 6; A = value; W = W2; bias = b2; out = vp; }

  const int tx = t & 31, ty = t >> 5;          // col-pair, row-quad
  const int aar = t >> 3, aac = (t & 7) << 2;  // A: row 0..63, k-quad
  const int bbr = t >> 4, bbc = (t & 15) << 2; // B: k-row 0..31, n-quad

  float4 ra, rb;
  ra = *(const float4*)(A + (size_t)(row0 + aar) * DD + aac);
  rb = *(const float4*)(W + (size_t)bbr * DD + bn + bbc);
  {
#pragma unroll
    for (int c = 0; c < 4; ++c) {
      const int k = aac + c;
      As[0][k][aar ^ (((k >> 2) & 7) << 2)] = (&ra.x)[c];
    }
    *(float4*)&Bs[0][bbr][bbc] = rb;
  }
  __syncthreads();

  float acc[4][2] = {{0.f,0.f},{0.f,0.f},{0.f,0.f},{0.f,0.f}};
  int p = 0;

  for (int k0 = 0; k0 < 256; k0 += 32) {
    const bool more = (k0 + 32) < 256;
    if (more) {
      ra = *(const float4*)(A + (size_t)(row0 + aar) * DD + k0 + 32 + aac);
      rb = *(const float4*)(W + (size_t)(k0 + 32 + bbr) * DD + bn + bbc);
    }
#pragma unroll
    for (int k = 0; k < 32; ++k) {
      float4 aq = *(const float4*)&As[p][k][(ty << 2) ^ (((k >> 2) & 7) << 2)];
      float2 bq = *(const float2*)&Bs[p][k][tx << 1];
      acc[0][0] = fmaf(aq.x, bq.x, acc[0][0]); acc[0][1] = fmaf(aq.x, bq.y, acc[0][1]);
      acc[1][0] = fmaf(aq.y, bq.x, acc[1][0]); acc[1][1] = fmaf(aq.y, bq.y, acc[1][1]);
      acc[2][0] = fmaf(aq.z, bq.x, acc[2][0]); acc[2][1] = fmaf(aq.z, bq.y, acc[2][1]);
      acc[3][0] = fmaf(aq.w, bq.x, acc[3][0]); acc[3][1] = fmaf(aq.w, bq.y, acc[3][1]);
    }
    if (more) {
      const int q = p ^ 1;
#pragma unroll
      for (int c = 0; c < 4; ++c) {
        const int k = aac + c;
        As[q][k][aar ^ (((k >> 2) & 7) << 2)] = (&ra.x)[c];
      }
      *(float4*)&Bs[q][bbr][bbc] = rb;
      __syncthreads();
      p = q;
    }
  }

  float2 bvv = *(const float2*)&bias[bn + (tx << 1)];
#pragma unroll
  for (int r = 0; r < 4; ++r) {
    float2 o;
    o.x = fast_exp2(scale * (acc[r][0] + bvv.x));
    o.y = fast_exp2(scale * (acc[r][1] + bvv.y));
    *(float2*)(out + (size_t)(row0 + (ty << 2) + r) * DD + bn + (tx << 1)) = o;
  }
}

// ---------------------------------------------------------------------------
// Fused score + softmax + context + concat + transposed alignment.
// R2 monolith VERBATIM — best measured attn (46.6 us). R3-R8 established its
// ~47 us plateau is structural (ILP, blocks, waves, splits all neutral or
// worse; R8: occupancy 62% at same duration, so not latency-bound).
// ---------------------------------------------------------------------------
__global__ __launch_bounds__(512, 4) void attn_mono(
    const float* __restrict__ qp, const float* __restrict__ vp,
    const float* __restrict__ value, const float* __restrict__ query,
    float* __restrict__ out1, float* __restrict__ out2) {
  __shared__ float qs[4 * 256];
  __shared__ float alg[4 * ALGS];
  __shared__ float ctxp[8][4][256];

  const int t    = threadIdx.x;
  const int lane = t & 63;
  const int wv   = t >> 6;
  const int jj   = lane >> 2;
  const int dq   = lane & 3;
  const int bb   = blockIdx.x & 7;
  const int i0   = (blockIdx.x >> 3) << 2;

  const float* vpb = vp + (size_t)bb * TV * DD;
  const float* qb  = qp + (size_t)(bb * TQ + i0) * DD;

  if (t < 256) {
    const int qi = t >> 6, qc = (t & 63) << 2;
    *(float4*)&qs[qi * 256 + qc] = *(const float4*)(qb + (size_t)qi * DD + qc);
  }
  __syncthreads();

  const int jb = (wv << 4) + jj;
  const float* vr0 = vpb + (size_t)jb * DD + (dq << 2);
  const float* vr1 = vr0 + 128 * DD;
  const float* vr2 = vr0 + 256 * DD;
  const float* vr3 = vr0 + 384 * DD;
  const float* qlane = qs + (dq << 2);

  float acc[4][4] = {{0.f,0.f,0.f,0.f},{0.f,0.f,0.f,0.f},
                     {0.f,0.f,0.f,0.f},{0.f,0.f,0.f,0.f}};

#pragma unroll 4
  for (int k = 0; k < 16; ++k) {
    const int doff = k << 4;
    float4 q0 = *(const float4*)(qlane + 0 * 256 + doff);
    float4 q1 = *(const float4*)(qlane + 1 * 256 + doff);
    float4 q2 = *(const float4*)(qlane + 2 * 256 + doff);
    float4 q3 = *(const float4*)(qlane + 3 * 256 + doff);
#pragma unroll
    for (int jg = 0; jg < 4; ++jg) {
      const float* vrp = (jg == 0) ? vr0 : (jg == 1) ? vr1 : (jg == 2) ? vr2 : vr3;
      float4 v4 = *(const float4*)(vrp + doff);
#pragma unroll
      for (int i = 0; i < 4; ++i) {
        const float4 q4 = (i == 0) ? q0 : (i == 1) ? q1 : (i == 2) ? q2 : q3;
        float a = q4.x * v4.x, b = q4.y * v4.y;
        float c = q4.z * v4.z, d = q4.w * v4.w;
        float sab = a + b,  scd = c + d;
        float Q1 = fmaf(a, b, sab + 1.f);
        float Q2 = fmaf(c, d, scd + 1.f);
        float N  = fmaf(scd + 2.f, Q1, (sab + 2.f) * Q2);
        acc[i][jg] = fmaf(N, fast_rcp(Q1 * Q2), acc[i][jg]);
      }
    }
  }

#pragma unroll
  for (int i = 0; i < 4; ++i)
#pragma unroll
    for (int jg = 0; jg < 4; ++jg) {
      acc[i][jg] += __shfl_xor(acc[i][jg], 1, 64);
      acc[i][jg] += __shfl_xor(acc[i][jg], 2, 64);
    }
#pragma unroll
  for (int jg = 0; jg < 4; ++jg) {
    float x = (dq == 0) ? acc[0][jg] : (dq == 1) ? acc[1][jg]
            : (dq == 2) ? acc[2][jg] : acc[3][jg];
    alg[dq * ALGS + (jg << 7) + jb] = x;
  }

  const int f4 = (t & 63) << 2;
  const int s  = t >> 6;
  const float* vb  = value + (size_t)bb * TV * DD;
  const float* vsp = vb + (size_t)(s << 6) * DD + f4;

  float4 pv0 = *(const float4*)(vsp + 0 * DD);
  float4 pv1 = *(const float4*)(vsp + 1 * DD);
  float4 pv2 = *(const float4*)(vsp + 2 * DD);
  float4 pv3 = *(const float4*)(vsp + 3 * DD);

  __syncthreads();

  if (wv < 4) {
    float sv[8];
#pragma unroll
    for (int c = 0; c < 8; ++c) sv[c] = alg[wv * ALGS + (c << 6) + lane];
    float mn = sv[0];
#pragma unroll
    for (int c = 1; c < 8; ++c) mn = fminf(mn, sv[c]);
#pragma unroll
    for (int m = 1; m < 64; m <<= 1) mn = fminf(mn, __shfl_xor(mn, m, 64));

    const float CC = 2.8853900817779268f;
    float p[8];
    float sum = 0.f;
#pragma unroll
    for (int c = 0; c < 8; ++c) { p[c] = fast_exp2(CC * (mn - sv[c])); sum += p[c]; }
#pragma unroll
    for (int m = 1; m < 64; m <<= 1) sum += __shfl_xor(sum, m, 64);
    const float inv = fast_rcp(sum);
#pragma unroll
    for (int c = 0; c < 8; ++c) alg[wv * ALGS + (c << 6) + lane] = p[c] * inv;
  }
  __syncthreads();

  {
    const int j = t;
    float4 av = make_float4(alg[j], alg[ALGS + j], alg[2 * ALGS + j], alg[3 * ALGS + j]);
    *(float4*)(out2 + (size_t)(bb * TV + j) * TQ + i0) = av;
  }

  float c4[4][4] = {{0.f,0.f,0.f,0.f},{0.f,0.f,0.f,0.f},
                    {0.f,0.f,0.f,0.f},{0.f,0.f,0.f,0.f}};
  const int jbase = s << 6;
  {
#pragma unroll
    for (int i = 0; i < 4; ++i) {
      float4 ai = *(const float4*)&alg[i * ALGS + jbase];
      c4[i][0] = fmaf(ai.x, pv0.x, c4[i][0]); c4[i][1] = fmaf(ai.x, pv0.y, c4[i][1]);
      c4[i][2] = fmaf(ai.x, pv0.z, c4[i][2]); c4[i][3] = fmaf(ai.x, pv0.w, c4[i][3]);
      c4[i][0] = fmaf(ai.y, pv1.x, c4[i][0]); c4[i][1] = fmaf(ai.y, pv1.y, c4[i][1]);
      c4[i][2] = fmaf(ai.y, pv1.z, c4[i][2]); c4[i][3] = fmaf(ai.y, pv1.w, c4[i][3]);
      c4[i][0] = fmaf(ai.z, pv2.x, c4[i][0]); c4[i][1] = fmaf(ai.z, pv2.y, c4[i][1]);
      c4[i][2] = fmaf(ai.z, pv2.z, c4[i][2]); c4[i][3] = fmaf(ai.z, pv2.w, c4[i][3]);
      c4[i][0] = fmaf(ai.w, pv3.x, c4[i][0]); c4[i][1] = fmaf(ai.w, pv3.y, c4[i][1]);
      c4[i][2] = fmaf(ai.w, pv3.z, c4[i][2]); c4[i][3] = fmaf(ai.w, pv3.w, c4[i][3]);
    }
  }
#pragma unroll 4
  for (int u = 4; u < 64; u += 4) {
    float4 v0 = *(const float4*)(vsp + (size_t)(u + 0) * DD);
    float4 v1 = *(const float4*)(vsp + (size_t)(u + 1) * DD);
    float4 v2 = *(const float4*)(vsp + (size_t)(u + 2) * DD);
    float4 v3 = *(const float4*)(vsp + (size_t)(u + 3) * DD);
#pragma unroll
    for (int i = 0; i < 4; ++i) {
      float4 ai = *(const float4*)&alg[i * ALGS + jbase + u];
      c4[i][0] = fmaf(ai.x, v0.x, c4[i][0]); c4[i][1] = fmaf(ai.x, v0.y, c4[i][1]);
      c4[i][2] = fmaf(ai.x, v0.z, c4[i][2]); c4[i][3] = fmaf(ai.x, v0.w, c4[i][3]);
      c4[i][0] = fmaf(ai.y, v1.x, c4[i][0]); c4[i][1] = fmaf(ai.y, v1.y, c4[i][1]);
      c4[i][2] = fmaf(ai.y, v1.z, c4[i][2]); c4[i][3] = fmaf(ai.y, v1.w, c4[i][3]);
      c4[i][0] = fmaf(ai.z, v2.x, c4[i][0]); c4[i][1] = fmaf(ai.z, v2.y, c4[i][1]);
      c4[i][2] = fmaf(ai.z, v2.z, c4[i][2]); c4[i][3] = fmaf(ai.z, v2.w, c4[i][3]);
      c4[i][0] = fmaf(ai.w, v3.x, c4[i][0]); c4[i][1] = fmaf(ai.w, v3.y, c4[i][1]);
      c4[i][2] = fmaf(ai.w, v3.z, c4[i][2]); c4[i][3] = fmaf(ai.w, v3.w, c4[i][3]);
    }
  }
#pragma unroll
  for (int i = 0; i < 4; ++i)
    *(float4*)&ctxp[s][i][f4] = make_float4(c4[i][0], c4[i][1], c4[i][2], c4[i][3]);
  __syncthreads();

  const float* qg = query + (size_t)(bb * TQ + i0) * DD;
  float* o = out1 + (size_t)(bb * TQ + i0) * (2 * DD);
#pragma unroll
  for (int it = 0; it < 2; ++it) {
    const int slot = t + (it << 9);
    const int ri = slot >> 8;
    const int ff = slot & 255;
    float sum = 0.f;
#pragma unroll
    for (int ss = 0; ss < 8; ++ss) sum += ctxp[ss][ri][ff];
    o[ri * 512 + ff] = sum;
    o[ri * 512 + 256 + ff] = qg[ri * DD + ff];
  }
}

// ---------------------------------------------------------------------------
extern "C" void kernel_launch(void* const* d_in, const int* in_sizes, int n_in,
                              void* d_out, int out_size, void* d_ws, size_t ws_size,
                              hipStream_t stream) {
  const float* query = (const float*)d_in[0];  // [8,256,256]
  const float* value = (const float*)d_in[1];  // [8,512,256]
  const float* W1    = (const float*)d_in[2];  // [256,256]
  const float* b1    = (const float*)d_in[3];  // [256]
  const float* W2    = (const float*)d_in[4];  // [256,256]
  const float* b2    = (const float*)d_in[5];  // [256]

  float* out1 = (float*)d_out;                     // context concat [8,256,512]
  float* out2 = out1 + (size_t)B_ * TQ * 2 * DD;   // alignment_t   [8,512,256]

  float* qp = (float*)d_ws;                        // Eq: 2048*256 floats
  float* vp = qp + (size_t)B_ * TQ * DD;           // Ev: 4096*256 floats

  const float SC = 2.8853900817779268f;  // 2*log2(e): exp(2x) = exp2(SC*x)

  proj_fused<<<dim3(96, 4), 512, 0, stream>>>(query, value, W1, b1, W2, b2, qp, vp, SC);
  attn_mono<<<dim3(B_ * (TQ / 4)), 512, 0, stream>>>(qp, vp, value, query, out1, out2);
}

// Round 10
// 124.407 us; speedup vs baseline: 1.1314x; 1.0302x over previous
//
#include <hip/hip_runtime.h>

#define B_  8
#define TQ  256
#define TV  512
#define DD  256
#define ALGS 520  // alg row stride: quad-write banks {j,j+8,j+16,j+24} -> <=2-way = free

__device__ __forceinline__ float fast_exp2(float x) {
#if __has_builtin(__builtin_amdgcn_exp2f)
  return __builtin_amdgcn_exp2f(x);
#else
  return __exp2f(x);
#endif
}
__device__ __forceinline__ float fast_rcp(float x) {
#if __has_builtin(__builtin_amdgcn_rcpf)
  return __builtin_amdgcn_rcpf(x);
#else
  return 1.0f / x;
#endif
}

// ---------------------------------------------------------------------------
// Fused projections with EXP epilogue. THIS ROUND: 32x64 tiles -> grid
// (192,4) = 768 blocks = EXACTLY 3 blocks/CU (was 384 = 1.5/CU: a 2:1
// load-imbalance tail, makespan = 2 sequential blocks on half the CUs).
// 256 thr, thread = 2 rows x 4 cols. Same k-summation order per output
// (bitwise-identical results), same LDS swizzle pattern as validated code.
// ---------------------------------------------------------------------------
__global__ __launch_bounds__(256) void proj_fused(
    const float* __restrict__ query, const float* __restrict__ value,
    const float* __restrict__ W1, const float* __restrict__ b1,
    const float* __restrict__ W2, const float* __restrict__ b2,
    float* __restrict__ qp, float* __restrict__ vp, float scale) {
  __shared__ float As[2][32][32];  // [p][k][m ^ sw(k)]
  __shared__ float Bs[2][32][64];  // [p][k][n]
  const int t  = threadIdx.x;
  const int rt = blockIdx.x;       // 0..191 row-tile (32 rows each)
  const int bn = blockIdx.y << 6;

  const float* A; const float* W; const float* bias; float* out; int row0;
  if (rt < 64) { row0 = rt << 5;        A = query; W = W1; bias = b1; out = qp; }
  else         { row0 = (rt - 64) << 5; A = value; W = W2; bias = b2; out = vp; }

  const int tx = t & 15, ty = t >> 4;          // col-quad, row-pair
  const int aar = t >> 3, aac = (t & 7) << 2;  // A: row 0..31, k-quad
  const int bbr = t >> 4, bbc = (t & 15) << 2; // B: k-row 0..15 (+16), n-quad

  float4 ra, rb0, rb1;
  ra  = *(const float4*)(A + (size_t)(row0 + aar) * DD + aac);
  rb0 = *(const float4*)(W + (size_t)bbr * DD + bn + bbc);
  rb1 = *(const float4*)(W + (size_t)(bbr + 16) * DD + bn + bbc);
  {
#pragma unroll
    for (int c = 0; c < 4; ++c) {
      const int k = aac + c;
      As[0][k][aar ^ (((k >> 2) & 7) << 2)] = (&ra.x)[c];
    }
    *(float4*)&Bs[0][bbr][bbc]      = rb0;
    *(float4*)&Bs[0][bbr + 16][bbc] = rb1;
  }
  __syncthreads();

  float acc[2][4] = {{0.f,0.f,0.f,0.f},{0.f,0.f,0.f,0.f}};
  int p = 0;

  for (int k0 = 0; k0 < 256; k0 += 32) {
    const bool more = (k0 + 32) < 256;
    if (more) {
      ra  = *(const float4*)(A + (size_t)(row0 + aar) * DD + k0 + 32 + aac);
      rb0 = *(const float4*)(W + (size_t)(k0 + 32 + bbr) * DD + bn + bbc);
      rb1 = *(const float4*)(W + (size_t)(k0 + 48 + bbr) * DD + bn + bbc);
    }
#pragma unroll
    for (int k = 0; k < 32; ++k) {
      float2 aq = *(const float2*)&As[p][k][(ty << 1) ^ (((k >> 2) & 7) << 2)];
      float4 bq = *(const float4*)&Bs[p][k][tx << 2];
      acc[0][0] = fmaf(aq.x, bq.x, acc[0][0]); acc[0][1] = fmaf(aq.x, bq.y, acc[0][1]);
      acc[0][2] = fmaf(aq.x, bq.z, acc[0][2]); acc[0][3] = fmaf(aq.x, bq.w, acc[0][3]);
      acc[1][0] = fmaf(aq.y, bq.x, acc[1][0]); acc[1][1] = fmaf(aq.y, bq.y, acc[1][1]);
      acc[1][2] = fmaf(aq.y, bq.z, acc[1][2]); acc[1][3] = fmaf(aq.y, bq.w, acc[1][3]);
    }
    if (more) {
      const int q = p ^ 1;
#pragma unroll
      for (int c = 0; c < 4; ++c) {
        const int k = aac + c;
        As[q][k][aar ^ (((k >> 2) & 7) << 2)] = (&ra.x)[c];
      }
      *(float4*)&Bs[q][bbr][bbc]      = rb0;
      *(float4*)&Bs[q][bbr + 16][bbc] = rb1;
      __syncthreads();
      p = q;
    }
  }

  float4 bvv = *(const float4*)&bias[bn + (tx << 2)];
#pragma unroll
  for (int r = 0; r < 2; ++r) {
    float4 o;
    o.x = fast_exp2(scale * (acc[r][0] + bvv.x));
    o.y = fast_exp2(scale * (acc[r][1] + bvv.y));
    o.z = fast_exp2(scale * (acc[r][2] + bvv.z));
    o.w = fast_exp2(scale * (acc[r][3] + bvv.w));
    *(float4*)(out + (size_t)(row0 + (ty << 1) + r) * DD + bn + (tx << 2)) = o;
  }
}

// ---------------------------------------------------------------------------
// Fused score + softmax + context + concat + transposed alignment.
// R2 monolith VERBATIM — best measured attn (45.4-46.6 us). R3-R8 established
// its plateau is structural (ILP, blocks, waves, splits all neutral/worse;
// R8: occupancy 62% at same duration -> not latency-bound).
// ---------------------------------------------------------------------------
__global__ __launch_bounds__(512, 4) void attn_mono(
    const float* __restrict__ qp, const float* __restrict__ vp,
    const float* __restrict__ value, const float* __restrict__ query,
    float* __restrict__ out1, float* __restrict__ out2) {
  __shared__ float qs[4 * 256];
  __shared__ float alg[4 * ALGS];
  __shared__ float ctxp[8][4][256];

  const int t    = threadIdx.x;
  const int lane = t & 63;
  const int wv   = t >> 6;
  const int jj   = lane >> 2;
  const int dq   = lane & 3;
  const int bb   = blockIdx.x & 7;
  const int i0   = (blockIdx.x >> 3) << 2;

  const float* vpb = vp + (size_t)bb * TV * DD;
  const float* qb  = qp + (size_t)(bb * TQ + i0) * DD;

  if (t < 256) {
    const int qi = t >> 6, qc = (t & 63) << 2;
    *(float4*)&qs[qi * 256 + qc] = *(const float4*)(qb + (size_t)qi * DD + qc);
  }
  __syncthreads();

  const int jb = (wv << 4) + jj;
  const float* vr0 = vpb + (size_t)jb * DD + (dq << 2);
  const float* vr1 = vr0 + 128 * DD;
  const float* vr2 = vr0 + 256 * DD;
  const float* vr3 = vr0 + 384 * DD;
  const float* qlane = qs + (dq << 2);

  float acc[4][4] = {{0.f,0.f,0.f,0.f},{0.f,0.f,0.f,0.f},
                     {0.f,0.f,0.f,0.f},{0.f,0.f,0.f,0.f}};

#pragma unroll 4
  for (int k = 0; k < 16; ++k) {
    const int doff = k << 4;
    float4 q0 = *(const float4*)(qlane + 0 * 256 + doff);
    float4 q1 = *(const float4*)(qlane + 1 * 256 + doff);
    float4 q2 = *(const float4*)(qlane + 2 * 256 + doff);
    float4 q3 = *(const float4*)(qlane + 3 * 256 + doff);
#pragma unroll
    for (int jg = 0; jg < 4; ++jg) {
      const float* vrp = (jg == 0) ? vr0 : (jg == 1) ? vr1 : (jg == 2) ? vr2 : vr3;
      float4 v4 = *(const float4*)(vrp + doff);
#pragma unroll
      for (int i = 0; i < 4; ++i) {
        const float4 q4 = (i == 0) ? q0 : (i == 1) ? q1 : (i == 2) ? q2 : q3;
        float a = q4.x * v4.x, b = q4.y * v4.y;
        float c = q4.z * v4.z, d = q4.w * v4.w;
        float sab = a + b,  scd = c + d;
        float Q1 = fmaf(a, b, sab + 1.f);
        float Q2 = fmaf(c, d, scd + 1.f);
        float N  = fmaf(scd + 2.f, Q1, (sab + 2.f) * Q2);
        acc[i][jg] = fmaf(N, fast_rcp(Q1 * Q2), acc[i][jg]);
      }
    }
  }

#pragma unroll
  for (int i = 0; i < 4; ++i)
#pragma unroll
    for (int jg = 0; jg < 4; ++jg) {
      acc[i][jg] += __shfl_xor(acc[i][jg], 1, 64);
      acc[i][jg] += __shfl_xor(acc[i][jg], 2, 64);
    }
#pragma unroll
  for (int jg = 0; jg < 4; ++jg) {
    float x = (dq == 0) ? acc[0][jg] : (dq == 1) ? acc[1][jg]
            : (dq == 2) ? acc[2][jg] : acc[3][jg];
    alg[dq * ALGS + (jg << 7) + jb] = x;
  }

  const int f4 = (t & 63) << 2;
  const int s  = t >> 6;
  const float* vb  = value + (size_t)bb * TV * DD;
  const float* vsp = vb + (size_t)(s << 6) * DD + f4;

  float4 pv0 = *(const float4*)(vsp + 0 * DD);
  float4 pv1 = *(const float4*)(vsp + 1 * DD);
  float4 pv2 = *(const float4*)(vsp + 2 * DD);
  float4 pv3 = *(const float4*)(vsp + 3 * DD);

  __syncthreads();

  if (wv < 4) {
    float sv[8];
#pragma unroll
    for (int c = 0; c < 8; ++c) sv[c] = alg[wv * ALGS + (c << 6) + lane];
    float mn = sv[0];
#pragma unroll
    for (int c = 1; c < 8; ++c) mn = fminf(mn, sv[c]);
#pragma unroll
    for (int m = 1; m < 64; m <<= 1) mn = fminf(mn, __shfl_xor(mn, m, 64));

    const float CC = 2.8853900817779268f;
    float p[8];
    float sum = 0.f;
#pragma unroll
    for (int c = 0; c < 8; ++c) { p[c] = fast_exp2(CC * (mn - sv[c])); sum += p[c]; }
#pragma unroll
    for (int m = 1; m < 64; m <<= 1) sum += __shfl_xor(sum, m, 64);
    const float inv = fast_rcp(sum);
#pragma unroll
    for (int c = 0; c < 8; ++c) alg[wv * ALGS + (c << 6) + lane] = p[c] * inv;
  }
  __syncthreads();

  {
    const int j = t;
    float4 av = make_float4(alg[j], alg[ALGS + j], alg[2 * ALGS + j], alg[3 * ALGS + j]);
    *(float4*)(out2 + (size_t)(bb * TV + j) * TQ + i0) = av;
  }

  float c4[4][4] = {{0.f,0.f,0.f,0.f},{0.f,0.f,0.f,0.f},
                    {0.f,0.f,0.f,0.f},{0.f,0.f,0.f,0.f}};
  const int jbase = s << 6;
  {
#pragma unroll
    for (int i = 0; i < 4; ++i) {
      float4 ai = *(const float4*)&alg[i * ALGS + jbase];
      c4[i][0] = fmaf(ai.x, pv0.x, c4[i][0]); c4[i][1] = fmaf(ai.x, pv0.y, c4[i][1]);
      c4[i][2] = fmaf(ai.x, pv0.z, c4[i][2]); c4[i][3] = fmaf(ai.x, pv0.w, c4[i][3]);
      c4[i][0] = fmaf(ai.y, pv1.x, c4[i][0]); c4[i][1] = fmaf(ai.y, pv1.y, c4[i][1]);
      c4[i][2] = fmaf(ai.y, pv1.z, c4[i][2]); c4[i][3] = fmaf(ai.y, pv1.w, c4[i][3]);
      c4[i][0] = fmaf(ai.z, pv2.x, c4[i][0]); c4[i][1] = fmaf(ai.z, pv2.y, c4[i][1]);
      c4[i][2] = fmaf(ai.z, pv2.z, c4[i][2]); c4[i][3] = fmaf(ai.z, pv2.w, c4[i][3]);
      c4[i][0] = fmaf(ai.w, pv3.x, c4[i][0]); c4[i][1] = fmaf(ai.w, pv3.y, c4[i][1]);
      c4[i][2] = fmaf(ai.w, pv3.z, c4[i][2]); c4[i][3] = fmaf(ai.w, pv3.w, c4[i][3]);
    }
  }
#pragma unroll 4
  for (int u = 4; u < 64; u += 4) {
    float4 v0 = *(const float4*)(vsp + (size_t)(u + 0) * DD);
    float4 v1 = *(const float4*)(vsp + (size_t)(u + 1) * DD);
    float4 v2 = *(const float4*)(vsp + (size_t)(u + 2) * DD);
    float4 v3 = *(const float4*)(vsp + (size_t)(u + 3) * DD);
#pragma unroll
    for (int i = 0; i < 4; ++i) {
      float4 ai = *(const float4*)&alg[i * ALGS + jbase + u];
      c4[i][0] = fmaf(ai.x, v0.x, c4[i][0]); c4[i][1] = fmaf(ai.x, v0.y, c4[i][1]);
      c4[i][2] = fmaf(ai.x, v0.z, c4[i][2]); c4[i][3] = fmaf(ai.x, v0.w, c4[i][3]);
      c4[i][0] = fmaf(ai.y, v1.x, c4[i][0]); c4[i][1] = fmaf(ai.y, v1.y, c4[i][1]);
      c4[i][2] = fmaf(ai.y, v1.z, c4[i][2]); c4[i][3] = fmaf(ai.y, v1.w, c4[i][3]);
      c4[i][0] = fmaf(ai.z, v2.x, c4[i][0]); c4[i][1] = fmaf(ai.z, v2.y, c4[i][1]);
      c4[i][2] = fmaf(ai.z, v2.z, c4[i][2]); c4[i][3] = fmaf(ai.z, v2.w, c4[i][3]);
      c4[i][0] = fmaf(ai.w, v3.x, c4[i][0]); c4[i][1] = fmaf(ai.w, v3.y, c4[i][1]);
      c4[i][2] = fmaf(ai.w, v3.z, c4[i][2]); c4[i][3] = fmaf(ai.w, v3.w, c4[i][3]);
    }
  }
#pragma unroll
  for (int i = 0; i < 4; ++i)
    *(float4*)&ctxp[s][i][f4] = make_float4(c4[i][0], c4[i][1], c4[i][2], c4[i][3]);
  __syncthreads();

  const float* qg = query + (size_t)(bb * TQ + i0) * DD;
  float* o = out1 + (size_t)(bb * TQ + i0) * (2 * DD);
#pragma unroll
  for (int it = 0; it < 2; ++it) {
    const int slot = t + (it << 9);
    const int ri = slot >> 8;
    const int ff = slot & 255;
    float sum = 0.f;
#pragma unroll
    for (int ss = 0; ss < 8; ++ss) sum += ctxp[ss][ri][ff];
    o[ri * 512 + ff] = sum;
    o[ri * 512 + 256 + ff] = qg[ri * DD + ff];
  }
}

// ---------------------------------------------------------------------------
extern "C" void kernel_launch(void* const* d_in, const int* in_sizes, int n_in,
                              void* d_out, int out_size, void* d_ws, size_t ws_size,
                              hipStream_t stream) {
  const float* query = (const float*)d_in[0];  // [8,256,256]
  const float* value = (const float*)d_in[1];  // [8,512,256]
  const float* W1    = (const float*)d_in[2];  // [256,256]
  const float* b1    = (const float*)d_in[3];  // [256]
  const float* W2    = (const float*)d_in[4];  // [256,256]
  const float* b2    = (const float*)d_in[5];  // [256]

  float* out1 = (float*)d_out;                     // context concat [8,256,512]
  float* out2 = out1 + (size_t)B_ * TQ * 2 * DD;   // alignment_t   [8,512,256]

  float* qp = (float*)d_ws;                        // Eq: 2048*256 floats
  float* vp = qp + (size_t)B_ * TQ * DD;           // Ev: 4096*256 floats

  const float SC = 2.8853900817779268f;  // 2*log2(e): exp(2x) = exp2(SC*x)

  proj_fused<<<dim3(192, 4), 256, 0, stream>>>(query, value, W1, b1, W2, b2, qp, vp, SC);
  attn_mono<<<dim3(B_ * (TQ / 4)), 512, 0, stream>>>(qp, vp, value, query, out1, out2);
}